// Round 8
// baseline (1443.937 us; speedup 1.0000x reference)
//
#include <hip/hip_runtime.h>
#include <hip/hip_bf16.h>

#define Ecnt 120000
#define Ncnt 15000
#define Tcnt 500000

typedef __attribute__((ext_vector_type(8))) short short8;
typedef __attribute__((ext_vector_type(4))) float floatx4;

__device__ __forceinline__ floatx4 mfma16(short8 a, short8 b, floatx4 c) {
    return __builtin_amdgcn_mfma_f32_16x16x32_bf16(a, b, c, 0, 0, 0);
}

__device__ __forceinline__ short f2bf(float f) {
    __hip_bfloat16 b = __float2bfloat16(f);
    short s;
    __builtin_memcpy(&s, &b, 2);
    return s;
}

__device__ __forceinline__ float bf2f(short s) {
    unsigned u = ((unsigned)(unsigned short)s) << 16;
    float f;
    __builtin_memcpy(&f, &u, 4);
    return f;
}

__device__ __forceinline__ unsigned pack2(float x, float y) {
    return (unsigned)(unsigned short)f2bf(x) | ((unsigned)(unsigned short)f2bf(y) << 16);
}

// bf16 MFMA tile swizzle: byte-col XOR (row&15)<<4, BOTH sides, bijective in
// 256B-aligned windows (128-short rows ok; 256-short rows ok for bc<=304).
__device__ __forceinline__ int sidx(int row, int bc) {
    return row * 128 + (((bc) ^ ((row & 15) << 4)) >> 1);
}
__device__ __forceinline__ int sidxg(int row, int bc, int ldshorts) {
    return row * ldshorts + (((bc) ^ ((row & 15) << 4)) >> 1);
}

__device__ __forceinline__ void stage64x128(const float* __restrict__ src, size_t row0,
                                            short* __restrict__ lds, int tid) {
    #pragma unroll
    for (int it = 0; it < 8; ++it) {
        int chunk = tid + it * 256;
        int r = chunk >> 5, c4 = chunk & 31;
        float4 v = *(const float4*)&src[(row0 + r) * 128 + c4 * 4];
        *(uint2*)&lds[sidx(r, c4 * 8)] = make_uint2(pack2(v.x, v.y), pack2(v.z, v.w));
    }
}

__device__ __forceinline__ void stage_bf(const short* __restrict__ src, size_t row0,
                                         short* __restrict__ lds, int tid) {
    #pragma unroll
    for (int it = 0; it < 4; ++it) {
        int chunk = tid + it * 256;
        int r = chunk >> 4, cg = chunk & 15;
        uint4 v = *(const uint4*)&src[(row0 + r) * 128 + cg * 8];
        *(uint4*)&lds[sidx(r, cg * 16)] = v;
    }
}

// 8-column-tile GEMM with 2-deep weight prefetch
template<int NKB, int K>
__device__ __forceinline__ void colmm8_pf(const short8 a[NKB], const short* __restrict__ wcol,
                                          floatx4 out[8]) {
    short8 w[2][NKB];
    #pragma unroll
    for (int kb = 0; kb < NKB; ++kb) w[0][kb] = *(const short8*)(wcol + kb * 32);
    #pragma unroll
    for (int kb = 0; kb < NKB; ++kb) w[1][kb] = *(const short8*)(wcol + 16 * K + kb * 32);
    #pragma unroll
    for (int c = 0; c < 8; ++c) {
        floatx4 acc = {0.f, 0.f, 0.f, 0.f};
        #pragma unroll
        for (int kb = 0; kb < NKB; ++kb) acc = mfma16(a[kb], w[c & 1][kb], acc);
        out[c] = acc;
        if (c + 2 < 8) {
            #pragma unroll
            for (int kb = 0; kb < NKB; ++kb)
                w[c & 1][kb] = *(const short8*)(wcol + (size_t)(c + 2) * 16 * K + kb * 32);
        }
    }
}

// ---------------- small kernels ----------------

__launch_bounds__(256)
__global__ void sentinel_k(float* o, float v) { o[0] = v; }

__launch_bounds__(256)
__global__ void atype_k(const float* __restrict__ af, int* __restrict__ atype) {
    int n = blockIdx.x * 256 + threadIdx.x;
    if (n >= Ncnt) return;
    const float* r = af + (size_t)n * 133;
    int best = 0; float bv = r[0];
    for (int k = 1; k < 100; ++k) { float v = r[k]; if (v > bv) { bv = v; best = k; } }
    atype[n] = best;
}

__launch_bounds__(128)
__global__ void pemb_k(const float* __restrict__ emb, const float* __restrict__ W,
                       float* __restrict__ P1, float* __restrict__ P2) {
    int r = blockIdx.x, c = threadIdx.x;
    __shared__ float er[128];
    er[c] = emb[r * 128 + c];
    __syncthreads();
    float a1 = 0.f, a2 = 0.f;
    for (int k = 0; k < 128; ++k) {
        float e = er[k];
        a1 = fmaf(e, W[k * 128 + c], a1);
        a2 = fmaf(e, W[(128 + k) * 128 + c], a2);
    }
    P1[r * 128 + c] = a1;
    P2[r * 128 + c] = a2;
}

__launch_bounds__(256)
__global__ void rbf0_k(const float* __restrict__ dist, const float* __restrict__ freq,
                       float* __restrict__ rbf0) {
    int e = blockIdx.x * 256 + threadIdx.x;
    if (e >= Ecnt) return;
    float x = dist[e] * 0.125f;
    float x2 = x * x;
    float x5 = x2 * x2 * x;
    float env = 1.f / x - 28.f * x5 + 48.f * x5 * x - 21.f * x5 * x2;
    if (!(x < 1.f)) env = 0.f;
    #pragma unroll
    for (int r = 0; r < 16; ++r)
        rbf0[(size_t)e * 16 + r] = env * sinf(freq[r] * x);
}

__launch_bounds__(256)
__global__ void rbfh_k(const float* __restrict__ rbf0, const float* __restrict__ W,
                       const float* __restrict__ bias, float* __restrict__ Y) {
    int gid = blockIdx.x * 256 + threadIdx.x;
    int e = gid >> 7, c = gid & 127;
    float acc = bias[c];
    #pragma unroll
    for (int k = 0; k < 16; ++k)
        acc = fmaf(rbf0[(size_t)e * 16 + k], W[k * 128 + c], acc);
    Y[(size_t)e * 128 + c] = fmaxf(acc, 0.f);
}

__launch_bounds__(256)
__global__ void scatatom_k(const float* __restrict__ msg, const int* __restrict__ eid,
                           const int* __restrict__ aid, float* __restrict__ am) {
    int gid = blockIdx.x * 256 + threadIdx.x;
    int e = gid >> 7, c = gid & 127;
    float v = msg[(size_t)eid[e] * 128 + c];
    atomicAdd(&am[(size_t)aid[e] * 128 + c], v);
}

// ---------------- sorting (CSR by target edge) ----------------

__launch_bounds__(256)
__global__ void hist_k(const int* __restrict__ idx, int* __restrict__ cnt) {
    int t = blockIdx.x * 256 + threadIdx.x;
    if (t < Tcnt) atomicAdd(&cnt[idx[t]], 1);
}

// in-place safe: reads cnt[i], writes basep[i] (same array allowed)
__launch_bounds__(256)
__global__ void scan1_k(int* __restrict__ cnt, int* __restrict__ btot) {
    __shared__ int s[256];
    int t = threadIdx.x, i = blockIdx.x * 256 + t;
    int v = (i < Ecnt) ? cnt[i] : 0;
    s[t] = v;
    #pragma unroll
    for (int off = 1; off < 256; off <<= 1) {
        __syncthreads();
        int nv = (t >= off) ? s[t - off] + s[t] : s[t];
        __syncthreads();
        s[t] = nv;
    }
    if (i < Ecnt) cnt[i] = s[t] - v;
    if (t == 255) btot[blockIdx.x] = s[255];
}

__launch_bounds__(512)
__global__ void scan2_k(const int* __restrict__ btot, int* __restrict__ boff, int nb) {
    __shared__ int s[512];
    int t = threadIdx.x;
    int v = (t < nb) ? btot[t] : 0;
    s[t] = v;
    #pragma unroll
    for (int off = 1; off < 512; off <<= 1) {
        __syncthreads();
        int nv = (t >= off) ? s[t - off] + s[t] : s[t];
        __syncthreads();
        s[t] = nv;
    }
    if (t < nb) boff[t] = s[t] - v;
}

// writes BOTH the permanent CSR starts (sstart, with sentinel) and the mutable cursor
__launch_bounds__(256)
__global__ void scan3_k(const int* __restrict__ basep, const int* __restrict__ boff,
                        int* __restrict__ sstart, int* __restrict__ cur) {
    int i = blockIdx.x * 256 + threadIdx.x;
    if (i < Ecnt) {
        int v = basep[i] + boff[i >> 8];
        sstart[i] = v;
        cur[i] = v;
    }
    if (i == 0) sstart[Ecnt] = Tcnt;
}

__launch_bounds__(256)
__global__ void perm_k(const int* __restrict__ idx, const float* __restrict__ angle,
                       int* __restrict__ cur, int* __restrict__ eids,
                       float* __restrict__ angs) {
    int t = blockIdx.x * 256 + threadIdx.x;
    if (t >= Tcnt) return;
    int e = idx[t];
    int p = atomicAdd(&cur[e], 1);
    eids[p] = e;
    angs[p] = angle[t];
}

// ---------------- weight conversion ----------------

struct WPack {
    const float* src[15];
    short* dst[15];
};
__launch_bounds__(256)
__global__ void transmany_k(WPack p) {
    int m = blockIdx.x >> 6;
    int i = ((blockIdx.x & 63) << 8) + threadIdx.x;
    int k = i >> 7, c = i & 127;
    p.dst[m][c * 128 + k] = f2bf(p.src[m][k * 128 + c]);
}

__launch_bounds__(256)
__global__ void transcvt_k(const float* __restrict__ W, short* __restrict__ out, int K) {
    int i = blockIdx.x * 256 + threadIdx.x;
    if (i >= K * 128) return;
    int k = i >> 7, c = i & 127;
    out[c * K + k] = f2bf(W[k * 128 + c]);
}

// r1 weight: K-index permuted by sigma(p) = (p&7)*16 + (p>>3) (ysort col order)
__launch_bounds__(256)
__global__ void transperm_k(const float* __restrict__ W, short* __restrict__ out) {
    int i = blockIdx.x * 256 + threadIdx.x;
    if (i >= 128 * 128) return;
    int n = i >> 7, p = i & 127;
    int k = (p & 7) * 16 + (p >> 3);
    out[i] = f2bf(W[k * 128 + n]);
}

// W_i1 [147][128] f32 -> [128][160] bf16 transposed, zero-padded
__launch_bounds__(256)
__global__ void transWi1_k(const float* __restrict__ W, short* __restrict__ out) {
    int i = blockIdx.x * 256 + threadIdx.x;
    if (i >= 128 * 160) return;
    int c = i / 160, k = i % 160;
    out[i] = (k < 147) ? f2bf(W[k * 128 + c]) : (short)0;
}

// ---------------- triplet path: NO SCATTER — writes per-triplet ysort ----------------
// ysort[t][p] where p = ccol*8 + c holds column sigma(p) = c*16+ccol.
__launch_bounds__(256)
__global__ void triplet_mfma_k(const float* __restrict__ angs, const int* __restrict__ eids,
                               const float* __restrict__ rbf0,
                               const short* __restrict__ W1t, const short* __restrict__ W2t,
                               const short* __restrict__ W3t, const float* __restrict__ upB,
                               const short* __restrict__ xdown, short* __restrict__ ysort) {
    __shared__ short lds[64 * 128];
    const int tid = threadIdx.x;
    const int lane = tid & 63;
    const int w = tid >> 6;
    const int row0 = blockIdx.x * 64;
    const int kgrp = lane >> 4;
    const int ccol = lane & 15;
    const int arow = w * 16 + ccol;
    const int cr0  = w * 16 + kgrp * 4;

    // wave-local sbf staging
    {
        int srow = row0 + arow;
        float cb[6], rb[16];
        if (srow < Tcnt) {
            float ang = angs[srow];
            int ge = eids[srow];
            float c1 = cosf(ang);
            cb[0] = 1.f; cb[1] = c1;
            #pragma unroll
            for (int a = 2; a < 6; ++a) cb[a] = 2.f * c1 * cb[a - 1] - cb[a - 2];
            #pragma unroll
            for (int i4 = 0; i4 < 4; ++i4) {
                float4 r4 = *(const float4*)&rbf0[(size_t)ge * 16 + i4 * 4];
                rb[i4*4+0] = r4.x; rb[i4*4+1] = r4.y; rb[i4*4+2] = r4.z; rb[i4*4+3] = r4.w;
            }
        } else {
            #pragma unroll
            for (int a = 0; a < 6; ++a) cb[a] = 0.f;
            #pragma unroll
            for (int q = 0; q < 16; ++q) rb[q] = 0.f;
        }
        #pragma unroll
        for (int m = 0; m < 12; ++m) {
            int v0 = kgrp * 24 + 2 * m;
            *(unsigned*)&lds[sidx(arow, 2 * v0)] =
                pack2(cb[v0 >> 4] * rb[v0 & 15], cb[(v0 + 1) >> 4] * rb[(v0 + 1) & 15]);
        }
    }

    int eidc[4];
    #pragma unroll
    for (int j = 0; j < 4; ++j) {
        int sr = row0 + cr0 + j;
        eidc[j] = (sr < Tcnt) ? eids[sr] : -1;
    }
    short8 xds[4];
    #pragma unroll
    for (int j = 0; j < 4; ++j) {
        if (eidc[j] >= 0)
            xds[j] = *(const short8*)&xdown[(size_t)eidc[j] * 128 + ccol * 8];
        else
            xds[j] = short8{0, 0, 0, 0, 0, 0, 0, 0};
    }

    floatx4 o[8];

    // GEMM1: s1 = relu(sbf @ W1), K=96
    {
        short8 a3[3];
        #pragma unroll
        for (int kb = 0; kb < 3; ++kb)
            a3[kb] = *(const short8*)&lds[sidx(arow, kb * 64 + kgrp * 16)];
        colmm8_pf<3, 96>(a3, W1t + ccol * 96 + kgrp * 8, o);
        #pragma unroll
        for (int c = 0; c < 8; ++c)
            #pragma unroll
            for (int j = 0; j < 4; ++j)
                lds[sidx(cr0 + j, 2 * (c * 16 + ccol))] = f2bf(fmaxf(o[c][j], 0.f));
    }

    // GEMM2: x = relu(s1 @ W2) * xd, K=128
    {
        short8 a4[4];
        #pragma unroll
        for (int kb = 0; kb < 4; ++kb)
            a4[kb] = *(const short8*)&lds[sidx(arow, kb * 64 + kgrp * 16)];
        colmm8_pf<4, 128>(a4, W2t + ccol * 128 + kgrp * 8, o);
        #pragma unroll
        for (int c = 0; c < 8; ++c)
            #pragma unroll
            for (int j = 0; j < 4; ++j)
                lds[sidx(cr0 + j, 2 * (c * 16 + ccol))] =
                    f2bf(fmaxf(o[c][j], 0.f) * bf2f(xds[j][c]));
    }

    // GEMM3: y = relu(x @ W3 + b) -> ysort (plain 16B stores, no atomics)
    {
        short8 a4[4];
        #pragma unroll
        for (int kb = 0; kb < 4; ++kb)
            a4[kb] = *(const short8*)&lds[sidx(arow, kb * 64 + kgrp * 16)];
        colmm8_pf<4, 128>(a4, W3t + ccol * 128 + kgrp * 8, o);
        float bu[8];
        #pragma unroll
        for (int c = 0; c < 8; ++c) bu[c] = upB[c * 16 + ccol];
        #pragma unroll
        for (int j = 0; j < 4; ++j) {
            int row = row0 + cr0 + j;
            if (row >= Tcnt) continue;
            short8 v;
            #pragma unroll
            for (int c = 0; c < 8; ++c)
                v[c] = f2bf(fmaxf(o[c][j] + bu[c], 0.f));
            *(short8*)&ysort[(size_t)row * 128 + ccol * 8] = v;
        }
    }
}

// ---------------- fused layerB: CSR segment-sum + res-MLP + msg update ----------------
// agg[e] = sum of ysort rows [sstart[e], sstart[e+1]) — exact f32, zero atomics.
// Then msg[e] += agg[e] + relu(relu(agg@r1'+b1)@r2+b2).  r1' has sigma baked in.
__launch_bounds__(256)
__global__ void layerBf_k(const short* __restrict__ ysort, const int* __restrict__ sstart,
                          const short* __restrict__ r1Wt, const float* __restrict__ r1B,
                          const short* __restrict__ r2Wt, const float* __restrict__ r2B,
                          float* __restrict__ msg) {
    __shared__ short ldsb[64 * 128];   // bf16 swizzled A (agg', then relu1)  16KB
    __shared__ float aggf[64 * 128];   // f32 agg (permuted col order)        32KB
    const int tid = threadIdx.x;
    const int lane = tid & 63, w = tid >> 6;
    const int row0 = blockIdx.x * 64;
    const int g16 = lane & 15;        // col-group (8 shorts)
    const int q   = lane >> 4;        // row sub-range 0..3

    // phase 1: segment sums (wave per edge, 4-way split + shfl reduce)
    for (int it = 0; it < 16; ++it) {
        int el = it * 4 + w;
        int e = row0 + el;
        int s = sstart[e], tEnd = sstart[e + 1];
        float acc[8] = {0.f, 0.f, 0.f, 0.f, 0.f, 0.f, 0.f, 0.f};
        for (int r = s + q; r < tEnd; r += 4) {
            short8 y = *(const short8*)&ysort[(size_t)r * 128 + g16 * 8];
            #pragma unroll
            for (int c = 0; c < 8; ++c) acc[c] += bf2f(y[c]);
        }
        #pragma unroll
        for (int c = 0; c < 8; ++c) {
            acc[c] += __shfl_xor(acc[c], 16);
            acc[c] += __shfl_xor(acc[c], 32);
        }
        if (q == 0) {
            unsigned u[4];
            #pragma unroll
            for (int h = 0; h < 4; ++h) u[h] = pack2(acc[2 * h], acc[2 * h + 1]);
            *(uint4*)&ldsb[sidx(el, g16 * 16)] = make_uint4(u[0], u[1], u[2], u[3]);
            *(float4*)&aggf[el * 128 + g16 * 8]     = make_float4(acc[0], acc[1], acc[2], acc[3]);
            *(float4*)&aggf[el * 128 + g16 * 8 + 4] = make_float4(acc[4], acc[5], acc[6], acc[7]);
        }
    }
    __syncthreads();

    const int kgrp = lane >> 4, ccol = lane & 15;
    const int arow = w * 16 + ccol;
    const int cr0  = w * 16 + kgrp * 4;
    short8 a1[4];
    #pragma unroll
    for (int kb = 0; kb < 4; ++kb)
        a1[kb] = *(const short8*)&ldsb[sidx(arow, kb * 64 + kgrp * 16)];
    floatx4 o[8];
    colmm8_pf<4, 128>(a1, r1Wt + ccol * 128 + kgrp * 8, o);
    #pragma unroll
    for (int c = 0; c < 8; ++c) {
        int colg = c * 16 + ccol;
        float b1 = r1B[colg];
        #pragma unroll
        for (int j = 0; j < 4; ++j)
            ldsb[sidx(cr0 + j, 2 * colg)] = f2bf(fmaxf(o[c][j] + b1, 0.f));
    }
    // wave-band-local: no barrier needed
    short8 a2[4];
    #pragma unroll
    for (int kb = 0; kb < 4; ++kb)
        a2[kb] = *(const short8*)&ldsb[sidx(arow, kb * 64 + kgrp * 16)];
    colmm8_pf<4, 128>(a2, r2Wt + ccol * 128 + kgrp * 8, o);
    #pragma unroll
    for (int c = 0; c < 8; ++c) {
        int colg = c * 16 + ccol;
        float b2 = r2B[colg];
        #pragma unroll
        for (int j = 0; j < 4; ++j) {
            size_t ofs = (size_t)(row0 + cr0 + j) * 128 + colg;
            float ag = aggf[(cr0 + j) * 128 + ccol * 8 + c];   // sigma^-1(colg)
            msg[ofs] = msg[ofs] + ag + fmaxf(o[c][j] + b2, 0.f);
        }
    }
}

// ---------------- initial message (K=160, pad 147) ----------------
__launch_bounds__(256, 3)
__global__ void imsg_k(const float* __restrict__ af, const float* __restrict__ ef,
                       const int* __restrict__ idx_j,
                       const short* __restrict__ Wt, const float* __restrict__ bias,
                       float* __restrict__ msg) {
    __shared__ short lds[64 * 256];
    const int tid = threadIdx.x;
    const int lane = tid & 63, w = tid >> 6;
    const int row0 = blockIdx.x * 64;

    #pragma unroll
    for (int it = 0; it < 5; ++it) {
        int chunk = tid + it * 256;
        int r = chunk / 20, cg = chunk % 20;
        int row = row0 + r;
        int g = idx_j[row];
        unsigned u[4];
        #pragma unroll
        for (int h = 0; h < 4; ++h) {
            int k0 = cg * 8 + 2 * h;
            int k1 = k0 + 1;
            float f0 = (k0 < 133) ? af[(size_t)g * 133 + k0]
                     : (k0 < 147) ? ef[(size_t)row * 14 + (k0 - 133)] : 0.f;
            float f1 = (k1 < 133) ? af[(size_t)g * 133 + k1]
                     : (k1 < 147) ? ef[(size_t)row * 14 + (k1 - 133)] : 0.f;
            u[h] = pack2(f0, f1);
        }
        *(uint4*)&lds[sidxg(r, cg * 16, 256)] = make_uint4(u[0], u[1], u[2], u[3]);
    }
    __syncthreads();

    const int kgrp = lane >> 4, ccol = lane & 15;
    const int arow = w * 16 + ccol;
    const int cr0  = w * 16 + kgrp * 4;
    short8 a[5];
    #pragma unroll
    for (int kb = 0; kb < 5; ++kb)
        a[kb] = *(const short8*)&lds[sidxg(arow, kb * 64 + kgrp * 16, 256)];
    floatx4 o[8];
    colmm8_pf<5, 160>(a, Wt + ccol * 160 + kgrp * 8, o);
    #pragma unroll
    for (int c = 0; c < 8; ++c) {
        int colg = c * 16 + ccol;
        float bv = bias[colg];
        #pragma unroll
        for (int j = 0; j < 4; ++j)
            msg[(size_t)(row0 + cr0 + j) * 128 + colg] = fmaxf(o[c][j] + bv, 0.f);
    }
}

// ---------------- layerA ----------------
__launch_bounds__(256, 3)
__global__ void layerA_k(const float* __restrict__ msg, const short* __restrict__ rbfe,
                         const short* __restrict__ kjWt, const float* __restrict__ kjB,
                         const short* __restrict__ rbf2Wt, const float* __restrict__ rbf2B,
                         const short* __restrict__ downWt, const float* __restrict__ downB,
                         short* __restrict__ xdown) {
    __shared__ short ldsM[64 * 128];
    __shared__ short ldsR[64 * 128];
    const int tid = threadIdx.x;
    const int lane = tid & 63, w = tid >> 6;
    const size_t row0 = (size_t)blockIdx.x * 64;
    stage64x128(msg, row0, ldsM, tid);
    stage_bf(rbfe, row0, ldsR, tid);
    __syncthreads();
    const int kgrp = lane >> 4, ccol = lane & 15;
    const int arow = w * 16 + ccol;
    const int cr0  = w * 16 + kgrp * 4;
    short8 aM[4], aR[4];
    #pragma unroll
    for (int kb = 0; kb < 4; ++kb) {
        aM[kb] = *(const short8*)&ldsM[sidx(arow, kb * 64 + kgrp * 16)];
        aR[kb] = *(const short8*)&ldsR[sidx(arow, kb * 64 + kgrp * 16)];
    }
    floatx4 oR[8], oK[8];
    colmm8_pf<4, 128>(aR, rbf2Wt + ccol * 128 + kgrp * 8, oR);
    colmm8_pf<4, 128>(aM, kjWt   + ccol * 128 + kgrp * 8, oK);
    #pragma unroll
    for (int c = 0; c < 8; ++c) {
        int colg = c * 16 + ccol;
        float rb = rbf2B[colg], kbb = kjB[colg];
        #pragma unroll
        for (int j = 0; j < 4; ++j) {
            float x = fmaxf(oK[c][j] + kbb, 0.f) * fmaxf(oR[c][j] + rb, 0.f);
            ldsM[sidx(cr0 + j, 2 * colg)] = f2bf(x);
        }
    }
    short8 aX[4];
    #pragma unroll
    for (int kb = 0; kb < 4; ++kb)
        aX[kb] = *(const short8*)&ldsM[sidx(arow, kb * 64 + kgrp * 16)];
    colmm8_pf<4, 128>(aX, downWt + ccol * 128 + kgrp * 8, oK);
    #pragma unroll
    for (int j = 0; j < 4; ++j) {
        short8 v;
        #pragma unroll
        for (int c = 0; c < 8; ++c)
            v[c] = f2bf(fmaxf(oK[c][j] + downB[c * 16 + ccol], 0.f));
        *(short8*)&xdown[(row0 + cr0 + j) * 128 + ccol * 8] = v;
    }
}

// ---------------- rbfe (bf16 out) ----------------
__launch_bounds__(256, 3)
__global__ void rbfe_k(const float* __restrict__ rbfh, const short* __restrict__ W3t,
                       const float* __restrict__ bias,
                       const int* __restrict__ idx_i, const int* __restrict__ idx_j,
                       const int* __restrict__ atype,
                       const float* __restrict__ P1, const float* __restrict__ P2,
                       short* __restrict__ out) {
    __shared__ short lds[64 * 128];
    const int tid = threadIdx.x;
    const int lane = tid & 63, w = tid >> 6;
    const size_t row0 = (size_t)blockIdx.x * 64;
    stage64x128(rbfh, row0, lds, tid);
    const int kgrp = lane >> 4, ccol = lane & 15;
    const int arow = w * 16 + ccol;
    const int cr0  = w * 16 + kgrp * 4;
    const float* p1p[4]; const float* p2p[4];
    #pragma unroll
    for (int j = 0; j < 4; ++j) {
        size_t row = row0 + cr0 + j;
        p1p[j] = P1 + (size_t)atype[idx_i[row]] * 128;
        p2p[j] = P2 + (size_t)atype[idx_j[row]] * 128;
    }
    __syncthreads();
    short8 a[4];
    #pragma unroll
    for (int kb = 0; kb < 4; ++kb)
        a[kb] = *(const short8*)&lds[sidx(arow, kb * 64 + kgrp * 16)];
    floatx4 o[8];
    colmm8_pf<4, 128>(a, W3t + ccol * 128 + kgrp * 8, o);
    #pragma unroll
    for (int c = 0; c < 8; ++c) {
        int colg = c * 16 + ccol;
        float bv = bias[colg];
        #pragma unroll
        for (int j = 0; j < 4; ++j)
            out[(row0 + cr0 + j) * 128 + colg] =
                f2bf(fmaxf(o[c][j] + bv + p1p[j][colg] + p2p[j][colg], 0.f));
    }
}

// ---------------- concat GEMM (fp32, final projection only) ----------------
__launch_bounds__(256)
__global__ void concatgemm_k(const float* __restrict__ IN1, int K1,
                             const float* __restrict__ IN2, int K2,
                             const float* __restrict__ W, const float* __restrict__ bias,
                             float* __restrict__ Y, int M) {
    __shared__ float xs[96 * 68];
    const int tid = threadIdx.x;
    const int row0 = blockIdx.x * 64;
    const int col8 = (tid & 15) * 8;
    const int r0 = (tid >> 4) * 4;
    const int K = K1 + K2;

    float acc[4][8];
    #pragma unroll
    for (int r = 0; r < 4; ++r)
        #pragma unroll
        for (int c = 0; c < 8; ++c) acc[r][c] = 0.f;

    for (int kb = 0; kb < K; kb += 96) {
        int kc = (K - kb < 96) ? (K - kb) : 96;
        __syncthreads();
        for (int idx = tid; idx < 64 * 96; idx += 256) {
            int r = idx / 96, kl = idx % 96;
            if (kl < kc) {
                int row = row0 + r;
                float v = 0.f;
                if (row < M) {
                    int kg = kb + kl;
                    v = (kg < K1) ? IN1[(size_t)row * K1 + kg]
                                  : IN2[(size_t)row * K2 + (kg - K1)];
                }
                xs[kl * 68 + r] = v;
            }
        }
        __syncthreads();
        for (int k = 0; k < kc; ++k) {
            float4 xv = *(const float4*)&xs[k * 68 + r0];
            const float* wr = &W[(size_t)(kb + k) * 128 + col8];
            float4 w0 = *(const float4*)wr;
            float4 w1 = *(const float4*)(wr + 4);
            float xr[4] = {xv.x, xv.y, xv.z, xv.w};
            float wc[8] = {w0.x, w0.y, w0.z, w0.w, w1.x, w1.y, w1.z, w1.w};
            #pragma unroll
            for (int r = 0; r < 4; ++r)
                #pragma unroll
                for (int c = 0; c < 8; ++c)
                    acc[r][c] = fmaf(xr[r], wc[c], acc[r][c]);
        }
    }

    float4 b0 = *(const float4*)&bias[col8];
    float4 b1 = *(const float4*)&bias[col8 + 4];
    float bb[8] = {b0.x, b0.y, b0.z, b0.w, b1.x, b1.y, b1.z, b1.w};
    #pragma unroll
    for (int r = 0; r < 4; ++r) {
        int row = row0 + r0 + r;
        if (row >= M) continue;
        float v[8];
        #pragma unroll
        for (int c = 0; c < 8; ++c) v[c] = fmaxf(acc[r][c] + bb[c], 0.f);
        *(float4*)&Y[(size_t)row * 128 + col8]     = make_float4(v[0], v[1], v[2], v[3]);
        *(float4*)&Y[(size_t)row * 128 + col8 + 4] = make_float4(v[4], v[5], v[6], v[7]);
    }
}

// ---------------- host ----------------

extern "C" void kernel_launch(void* const* d_in, const int* in_sizes, int n_in,
                              void* d_out, int out_size, void* d_ws, size_t ws_size,
                              hipStream_t stream) {
    const float* atom_feature = (const float*)d_in[0];
    const float* edge_feature = (const float*)d_in[1];
    const float* dist         = (const float*)d_in[2];
    const float* angle        = (const float*)d_in[3];
    const float* W_i1_w       = (const float*)d_in[4];
    const float* W_i1_b       = (const float*)d_in[5];
    const float* emb_table    = (const float*)d_in[6];
    const float* lin_rbf_w    = (const float*)d_in[7];
    const float* lin_rbf_b    = (const float*)d_in[8];
    const float* lin_emb_w    = (const float*)d_in[9];
    const float* lin_emb_b    = (const float*)d_in[10];
    const float* bessel_freq  = (const float*)d_in[11];
    const float* L_rbf2_w     = (const float*)d_in[12];
    const float* L_rbf2_b     = (const float*)d_in[13];
    const float* L_kj_w       = (const float*)d_in[14];
    const float* L_kj_b       = (const float*)d_in[15];
    const float* L_sbf1_w     = (const float*)d_in[16];
    const float* L_sbf2_w     = (const float*)d_in[17];
    const float* L_down_w     = (const float*)d_in[18];
    const float* L_down_b     = (const float*)d_in[19];
    const float* L_up_w       = (const float*)d_in[20];
    const float* L_up_b       = (const float*)d_in[21];
    const float* L_res1_w     = (const float*)d_in[22];
    const float* L_res1_b     = (const float*)d_in[23];
    const float* L_res2_w     = (const float*)d_in[24];
    const float* L_res2_b     = (const float*)d_in[25];
    const float* W_o_w        = (const float*)d_in[26];
    const float* W_o_b        = (const float*)d_in[27];
    const int* idx_i          = (const int*)d_in[28];
    const int* idx_j          = (const int*)d_in[29];
    const int* idx_kj         = (const int*)d_in[30];
    const int* ib_eid         = (const int*)d_in[32];
    const int* ib_atom        = (const int*)d_in[33];

    float* ws = (float*)d_ws;
    size_t off = 0;
    auto take = [&](size_t n) { float* p = ws + off; off += n; return p; };
    float* msg   = take((size_t)Ecnt * 128);
    short* rbfe  = (short*)take((size_t)Ecnt * 64);
    short* sxd   = (short*)take((size_t)Ecnt * 64);
    short* ysort = (short*)take((size_t)Tcnt * 64);      // 128 MB; rbf_h scratch + atomm alias
    float* rbf0b = take((size_t)Ecnt * 16);
    float* P1    = take(100 * 128);
    float* P2    = take(100 * 128);
    int*   atyp  = (int*)take(Ncnt);
    int*   cnts  = (int*)take(Ecnt);                     // becomes basep in-place
    int*   sstart= (int*)take(Ecnt + 1);
    int*   cur   = (int*)take(Ecnt);
    int*   btot  = (int*)take(512);
    int*   boff  = (int*)take(512);
    int*   eids  = (int*)take(Tcnt);
    float* angs  = take(Tcnt);
    short* wts   = (short*)take(160000);

    if (off * sizeof(float) > ws_size) {
        sentinel_k<<<1, 256, 0, stream>>>((float*)d_out, (float)ws_size);
        return;
    }

    float* rbfh_s = (float*)ysort;    // scratch before triplet use
    float* atomm  = (float*)ysort;    // alias: ysort dead after last layerBf

    const int GE  = Ecnt / 64;
    const int GN  = (Ncnt + 63) / 64;
    const int GT  = (Tcnt + 63) / 64;
    const int NBE = (Ecnt + 255) / 256;
    const int NBT = (Tcnt + 255) / 256;

    atype_k<<<(Ncnt + 255) / 256, 256, 0, stream>>>(atom_feature, atyp);
    pemb_k<<<100, 128, 0, stream>>>(emb_table, lin_emb_w, P1, P2);
    rbf0_k<<<NBE, 256, 0, stream>>>(dist, bessel_freq, rbf0b);

    hipMemsetAsync(cnts, 0, (size_t)Ecnt * sizeof(int), stream);
    hist_k<<<NBT, 256, 0, stream>>>(idx_kj, cnts);
    scan1_k<<<NBE, 256, 0, stream>>>(cnts, btot);             // in-place -> basep
    scan2_k<<<1, 512, 0, stream>>>(btot, boff, NBE);
    scan3_k<<<NBE, 256, 0, stream>>>(cnts, boff, sstart, cur);
    perm_k<<<NBT, 256, 0, stream>>>(idx_kj, angle, cur, eids, angs);

    short* p = wts;
    short* wt1[2]; short* wt2[2]; short* wt3[2];
    short* wkj[2]; short* wr2f[2]; short* wdn[2]; short* wr1[2]; short* wr2[2];
    for (int l = 0; l < 2; ++l) {
        wt1[l] = p; p += 96 * 128;
        wt2[l] = p; p += 128 * 128;
        wt3[l] = p; p += 128 * 128;
        wkj[l] = p; p += 128 * 128;
        wr2f[l] = p; p += 128 * 128;
        wdn[l] = p; p += 128 * 128;
        wr1[l] = p; p += 128 * 128;
        wr2[l] = p; p += 128 * 128;
    }
    short* wemb3 = p; p += 128 * 128;
    short* wi1t  = p; p += 128 * 160;

    WPack wp;
    int m = 0;
    for (int l = 0; l < 2; ++l) {
        wp.src[m] = L_sbf2_w + (size_t)l * 128 * 128; wp.dst[m++] = wt2[l];
        wp.src[m] = L_up_w   + (size_t)l * 128 * 128; wp.dst[m++] = wt3[l];
        wp.src[m] = L_kj_w   + (size_t)l * 128 * 128; wp.dst[m++] = wkj[l];
        wp.src[m] = L_rbf2_w + (size_t)l * 128 * 128; wp.dst[m++] = wr2f[l];
        wp.src[m] = L_down_w + (size_t)l * 128 * 128; wp.dst[m++] = wdn[l];
        wp.src[m] = L_res2_w + (size_t)l * 128 * 128; wp.dst[m++] = wr2[l];
    }
    wp.src[m] = lin_emb_w + 256 * 128; wp.dst[m++] = wemb3;   // m == 13
    transmany_k<<<13 * 64, 256, 0, stream>>>(wp);
    const int G96 = (96 * 128 + 255) / 256, G128 = (128 * 128 + 255) / 256;
    transcvt_k<<<G96, 256, 0, stream>>>(L_sbf1_w, wt1[0], 96);
    transcvt_k<<<G96, 256, 0, stream>>>(L_sbf1_w + (size_t)96 * 128, wt1[1], 96);
    transperm_k<<<G128, 256, 0, stream>>>(L_res1_w, wr1[0]);
    transperm_k<<<G128, 256, 0, stream>>>(L_res1_w + (size_t)128 * 128, wr1[1]);
    transWi1_k<<<(128 * 160 + 255) / 256, 256, 0, stream>>>(W_i1_w, wi1t);

    imsg_k<<<GE, 256, 0, stream>>>(atom_feature, edge_feature, idx_j, wi1t, W_i1_b, msg);
    rbfh_k<<<(Ecnt * 128) / 256, 256, 0, stream>>>(rbf0b, lin_rbf_w, lin_rbf_b, rbfh_s);
    rbfe_k<<<GE, 256, 0, stream>>>(rbfh_s, wemb3, lin_emb_b, idx_i, idx_j, atyp, P1, P2, rbfe);

    for (int l = 0; l < 2; ++l) {
        layerA_k<<<GE, 256, 0, stream>>>(msg, rbfe,
                                         wkj[l], L_kj_b + (size_t)l * 128,
                                         wr2f[l], L_rbf2_b + (size_t)l * 128,
                                         wdn[l], L_down_b + (size_t)l * 128, sxd);
        triplet_mfma_k<<<GT, 256, 0, stream>>>(angs, eids, rbf0b,
                                               wt1[l], wt2[l], wt3[l],
                                               L_up_b + (size_t)l * 128, sxd, ysort);
        layerBf_k<<<GE, 256, 0, stream>>>(ysort, sstart,
                                          wr1[l], L_res1_b + (size_t)l * 128,
                                          wr2[l], L_res2_b + (size_t)l * 128, msg);
    }

    hipMemsetAsync(atomm, 0, (size_t)Ncnt * 128 * sizeof(float), stream);
    scatatom_k<<<(Ecnt * 128) / 256, 256, 0, stream>>>(msg, ib_eid, ib_atom, atomm);
    concatgemm_k<<<GN, 256, 0, stream>>>(atom_feature, 133, atomm, 128,
                                         W_o_w, W_o_b, (float*)d_out, Ncnt);
}

// Round 9
// 1311.796 us; speedup vs baseline: 1.1007x; 1.1007x over previous
//
#include <hip/hip_runtime.h>
#include <hip/hip_bf16.h>

#define Ecnt 120000
#define Ncnt 15000
#define Tcnt 500000

typedef __attribute__((ext_vector_type(8))) short short8;
typedef __attribute__((ext_vector_type(4))) float floatx4;

__device__ __forceinline__ floatx4 mfma16(short8 a, short8 b, floatx4 c) {
    return __builtin_amdgcn_mfma_f32_16x16x32_bf16(a, b, c, 0, 0, 0);
}

__device__ __forceinline__ short f2bf(float f) {
    __hip_bfloat16 b = __float2bfloat16(f);
    short s;
    __builtin_memcpy(&s, &b, 2);
    return s;
}

__device__ __forceinline__ float bf2f(short s) {
    unsigned u = ((unsigned)(unsigned short)s) << 16;
    float f;
    __builtin_memcpy(&f, &u, 4);
    return f;
}

__device__ __forceinline__ unsigned pack2(float x, float y) {
    return (unsigned)(unsigned short)f2bf(x) | ((unsigned)(unsigned short)f2bf(y) << 16);
}

// bf16 MFMA tile swizzle: byte-col XOR (row&15)<<4, BOTH sides, bijective in
// 256B-aligned windows (128-short rows ok; 256-short rows ok for bc<=304).
__device__ __forceinline__ int sidx(int row, int bc) {
    return row * 128 + (((bc) ^ ((row & 15) << 4)) >> 1);
}
__device__ __forceinline__ int sidxg(int row, int bc, int ldshorts) {
    return row * ldshorts + (((bc) ^ ((row & 15) << 4)) >> 1);
}

__device__ __forceinline__ void stage64x128(const float* __restrict__ src, size_t row0,
                                            short* __restrict__ lds, int tid) {
    #pragma unroll
    for (int it = 0; it < 8; ++it) {
        int chunk = tid + it * 256;
        int r = chunk >> 5, c4 = chunk & 31;
        float4 v = *(const float4*)&src[(row0 + r) * 128 + c4 * 4];
        *(uint2*)&lds[sidx(r, c4 * 8)] = make_uint2(pack2(v.x, v.y), pack2(v.z, v.w));
    }
}

__device__ __forceinline__ void stage_bf(const short* __restrict__ src, size_t row0,
                                         short* __restrict__ lds, int tid) {
    #pragma unroll
    for (int it = 0; it < 4; ++it) {
        int chunk = tid + it * 256;
        int r = chunk >> 4, cg = chunk & 15;
        uint4 v = *(const uint4*)&src[(row0 + r) * 128 + cg * 8];
        *(uint4*)&lds[sidx(r, cg * 16)] = v;
    }
}

// 8-column-tile GEMM, single row-group, 2-deep weight prefetch (E-path kernels)
template<int NKB, int K>
__device__ __forceinline__ void colmm8_pf(const short8 a[NKB], const short* __restrict__ wcol,
                                          floatx4 out[8]) {
    short8 w[2][NKB];
    #pragma unroll
    for (int kb = 0; kb < NKB; ++kb) w[0][kb] = *(const short8*)(wcol + kb * 32);
    #pragma unroll
    for (int kb = 0; kb < NKB; ++kb) w[1][kb] = *(const short8*)(wcol + 16 * K + kb * 32);
    #pragma unroll
    for (int c = 0; c < 8; ++c) {
        floatx4 acc = {0.f, 0.f, 0.f, 0.f};
        #pragma unroll
        for (int kb = 0; kb < NKB; ++kb) acc = mfma16(a[kb], w[c & 1][kb], acc);
        out[c] = acc;
        if (c + 2 < 8) {
            #pragma unroll
            for (int kb = 0; kb < NKB; ++kb)
                w[c & 1][kb] = *(const short8*)(wcol + (size_t)(c + 2) * 16 * K + kb * 32);
        }
    }
}

// Dual row-group variant: each weight fragment feeds TWO MFMAs (2:1 MFMA:load).
// Epilogue lambda consumes each column-tile's pair of accumulators immediately.
template<int NKB, int K, typename Epi>
__device__ __forceinline__ void colmm8_dual(const short8 a0[NKB], const short8 a1[NKB],
                                            const short* __restrict__ wcol, Epi epi) {
    short8 w[2][NKB];
    #pragma unroll
    for (int kb = 0; kb < NKB; ++kb) w[0][kb] = *(const short8*)(wcol + kb * 32);
    #pragma unroll
    for (int kb = 0; kb < NKB; ++kb) w[1][kb] = *(const short8*)(wcol + 16 * K + kb * 32);
    #pragma unroll
    for (int c = 0; c < 8; ++c) {
        floatx4 acc0 = {0.f, 0.f, 0.f, 0.f};
        floatx4 acc1 = {0.f, 0.f, 0.f, 0.f};
        #pragma unroll
        for (int kb = 0; kb < NKB; ++kb) {
            acc0 = mfma16(a0[kb], w[c & 1][kb], acc0);
            acc1 = mfma16(a1[kb], w[c & 1][kb], acc1);
        }
        epi(c, acc0, acc1);
        if (c + 2 < 8) {
            #pragma unroll
            for (int kb = 0; kb < NKB; ++kb)
                w[c & 1][kb] = *(const short8*)(wcol + (size_t)(c + 2) * 16 * K + kb * 32);
        }
    }
}

// ---------------- small kernels ----------------

__launch_bounds__(256)
__global__ void sentinel_k(float* o, float v) { o[0] = v; }

__launch_bounds__(256)
__global__ void atype_k(const float* __restrict__ af, int* __restrict__ atype) {
    int n = blockIdx.x * 256 + threadIdx.x;
    if (n >= Ncnt) return;
    const float* r = af + (size_t)n * 133;
    int best = 0; float bv = r[0];
    for (int k = 1; k < 100; ++k) { float v = r[k]; if (v > bv) { bv = v; best = k; } }
    atype[n] = best;
}

__launch_bounds__(128)
__global__ void pemb_k(const float* __restrict__ emb, const float* __restrict__ W,
                       float* __restrict__ P1, float* __restrict__ P2) {
    int r = blockIdx.x, c = threadIdx.x;
    __shared__ float er[128];
    er[c] = emb[r * 128 + c];
    __syncthreads();
    float a1 = 0.f, a2 = 0.f;
    for (int k = 0; k < 128; ++k) {
        float e = er[k];
        a1 = fmaf(e, W[k * 128 + c], a1);
        a2 = fmaf(e, W[(128 + k) * 128 + c], a2);
    }
    P1[r * 128 + c] = a1;
    P2[r * 128 + c] = a2;
}

__launch_bounds__(256)
__global__ void rbf0_k(const float* __restrict__ dist, const float* __restrict__ freq,
                       float* __restrict__ rbf0) {
    int e = blockIdx.x * 256 + threadIdx.x;
    if (e >= Ecnt) return;
    float x = dist[e] * 0.125f;
    float x2 = x * x;
    float x5 = x2 * x2 * x;
    float env = 1.f / x - 28.f * x5 + 48.f * x5 * x - 21.f * x5 * x2;
    if (!(x < 1.f)) env = 0.f;
    #pragma unroll
    for (int r = 0; r < 16; ++r)
        rbf0[(size_t)e * 16 + r] = env * sinf(freq[r] * x);
}

__launch_bounds__(256)
__global__ void rbfh_k(const float* __restrict__ rbf0, const float* __restrict__ W,
                       const float* __restrict__ bias, float* __restrict__ Y) {
    int gid = blockIdx.x * 256 + threadIdx.x;
    int e = gid >> 7, c = gid & 127;
    float acc = bias[c];
    #pragma unroll
    for (int k = 0; k < 16; ++k)
        acc = fmaf(rbf0[(size_t)e * 16 + k], W[k * 128 + c], acc);
    Y[(size_t)e * 128 + c] = fmaxf(acc, 0.f);
}

__launch_bounds__(256)
__global__ void scatatom_k(const float* __restrict__ msg, const int* __restrict__ eid,
                           const int* __restrict__ aid, float* __restrict__ am) {
    int gid = blockIdx.x * 256 + threadIdx.x;
    int e = gid >> 7, c = gid & 127;
    float v = msg[(size_t)eid[e] * 128 + c];
    atomicAdd(&am[(size_t)aid[e] * 128 + c], v);
}

// ---------------- sorting (CSR by target edge) ----------------

__launch_bounds__(256)
__global__ void hist_k(const int* __restrict__ idx, int* __restrict__ cnt) {
    int t = blockIdx.x * 256 + threadIdx.x;
    if (t < Tcnt) atomicAdd(&cnt[idx[t]], 1);
}

__launch_bounds__(256)
__global__ void scan1_k(int* __restrict__ cnt, int* __restrict__ btot) {
    __shared__ int s[256];
    int t = threadIdx.x, i = blockIdx.x * 256 + t;
    int v = (i < Ecnt) ? cnt[i] : 0;
    s[t] = v;
    #pragma unroll
    for (int off = 1; off < 256; off <<= 1) {
        __syncthreads();
        int nv = (t >= off) ? s[t - off] + s[t] : s[t];
        __syncthreads();
        s[t] = nv;
    }
    if (i < Ecnt) cnt[i] = s[t] - v;
    if (t == 255) btot[blockIdx.x] = s[255];
}

__launch_bounds__(512)
__global__ void scan2_k(const int* __restrict__ btot, int* __restrict__ boff, int nb) {
    __shared__ int s[512];
    int t = threadIdx.x;
    int v = (t < nb) ? btot[t] : 0;
    s[t] = v;
    #pragma unroll
    for (int off = 1; off < 512; off <<= 1) {
        __syncthreads();
        int nv = (t >= off) ? s[t - off] + s[t] : s[t];
        __syncthreads();
        s[t] = nv;
    }
    if (t < nb) boff[t] = s[t] - v;
}

__launch_bounds__(256)
__global__ void scan3_k(const int* __restrict__ basep, const int* __restrict__ boff,
                        int* __restrict__ sstart, int* __restrict__ cur) {
    int i = blockIdx.x * 256 + threadIdx.x;
    if (i < Ecnt) {
        int v = basep[i] + boff[i >> 8];
        sstart[i] = v;
        cur[i] = v;
    }
    if (i == 0) sstart[Ecnt] = Tcnt;
}

__launch_bounds__(256)
__global__ void perm_k(const int* __restrict__ idx, const float* __restrict__ angle,
                       int* __restrict__ cur, int* __restrict__ eids,
                       float* __restrict__ angs) {
    int t = blockIdx.x * 256 + threadIdx.x;
    if (t >= Tcnt) return;
    int e = idx[t];
    int p = atomicAdd(&cur[e], 1);
    eids[p] = e;
    angs[p] = angle[t];
}

// ---------------- weight conversion ----------------

struct WPack {
    const float* src[15];
    short* dst[15];
};
__launch_bounds__(256)
__global__ void transmany_k(WPack p) {
    int m = blockIdx.x >> 6;
    int i = ((blockIdx.x & 63) << 8) + threadIdx.x;
    int k = i >> 7, c = i & 127;
    p.dst[m][c * 128 + k] = f2bf(p.src[m][k * 128 + c]);
}

__launch_bounds__(256)
__global__ void transcvt_k(const float* __restrict__ W, short* __restrict__ out, int K) {
    int i = blockIdx.x * 256 + threadIdx.x;
    if (i >= K * 128) return;
    int k = i >> 7, c = i & 127;
    out[c * K + k] = f2bf(W[k * 128 + c]);
}

// r1 weight: K-index permuted by sigma(p) = (p&7)*16 + (p>>3) (ysort col order)
__launch_bounds__(256)
__global__ void transperm_k(const float* __restrict__ W, short* __restrict__ out) {
    int i = blockIdx.x * 256 + threadIdx.x;
    if (i >= 128 * 128) return;
    int n = i >> 7, p = i & 127;
    int k = (p & 7) * 16 + (p >> 3);
    out[i] = f2bf(W[k * 128 + n]);
}

__launch_bounds__(256)
__global__ void transWi1_k(const float* __restrict__ W, short* __restrict__ out) {
    int i = blockIdx.x * 256 + threadIdx.x;
    if (i >= 128 * 160) return;
    int c = i / 160, k = i % 160;
    out[i] = (k < 147) ? f2bf(W[k * 128 + c]) : (short)0;
}

// ---------------- triplet path: 128-row tile, dual row-group (2:1 MFMA:load) ----------------
// Wave w owns rows [w*32, w*32+32) through all 3 GEMMs (barrier-free).
// ysort[t][p], p = ccol*8 + c, holds column sigma(p) = c*16+ccol.
__launch_bounds__(256)
__global__ void triplet_mfma_k(const float* __restrict__ angs, const int* __restrict__ eids,
                               const float* __restrict__ rbf0,
                               const short* __restrict__ W1t, const short* __restrict__ W2t,
                               const short* __restrict__ W3t, const float* __restrict__ upB,
                               const short* __restrict__ xdown, short* __restrict__ ysort) {
    __shared__ short lds[128 * 128];   // 32 KB
    const int tid = threadIdx.x;
    const int lane = tid & 63;
    const int w = tid >> 6;
    const int row0 = blockIdx.x * 128;
    const int kgrp = lane >> 4;
    const int ccol = lane & 15;
    const int ar0 = w * 32 + ccol;          // row-group 0 A-row
    const int ar1 = w * 32 + 16 + ccol;     // row-group 1 A-row
    const int cb0 = w * 32 + kgrp * 4;      // row-group 0 C-row base
    const int cb1 = w * 32 + 16 + kgrp * 4; // row-group 1 C-row base

    // wave-local staging: thread stages half a row (48 bf16 cols), row = tid>>1
    {
        int r = tid >> 1, h = tid & 1;
        int srow = row0 + r;
        float cb[6], rb[16];
        if (srow < Tcnt) {
            float ang = angs[srow];
            int ge = eids[srow];
            float c1 = cosf(ang);
            cb[0] = 1.f; cb[1] = c1;
            #pragma unroll
            for (int a = 2; a < 6; ++a) cb[a] = 2.f * c1 * cb[a - 1] - cb[a - 2];
            #pragma unroll
            for (int i4 = 0; i4 < 4; ++i4) {
                float4 r4 = *(const float4*)&rbf0[(size_t)ge * 16 + i4 * 4];
                rb[i4*4+0] = r4.x; rb[i4*4+1] = r4.y; rb[i4*4+2] = r4.z; rb[i4*4+3] = r4.w;
            }
        } else {
            #pragma unroll
            for (int a = 0; a < 6; ++a) cb[a] = 0.f;
            #pragma unroll
            for (int q = 0; q < 16; ++q) rb[q] = 0.f;
        }
        #pragma unroll
        for (int m = 0; m < 24; ++m) {
            int v0 = h * 48 + 2 * m;
            *(unsigned*)&lds[sidx(r, 2 * v0)] =
                pack2(cb[v0 >> 4] * rb[v0 & 15], cb[(v0 + 1) >> 4] * rb[(v0 + 1) & 15]);
        }
    }

    int eidc[2][4];
    #pragma unroll
    for (int g = 0; g < 2; ++g)
        #pragma unroll
        for (int j = 0; j < 4; ++j) {
            int sr = row0 + (g ? cb1 : cb0) + j;
            eidc[g][j] = (sr < Tcnt) ? eids[sr] : -1;
        }
    short8 xds[2][4];
    #pragma unroll
    for (int g = 0; g < 2; ++g)
        #pragma unroll
        for (int j = 0; j < 4; ++j) {
            if (eidc[g][j] >= 0)
                xds[g][j] = *(const short8*)&xdown[(size_t)eidc[g][j] * 128 + ccol * 8];
            else
                xds[g][j] = short8{0, 0, 0, 0, 0, 0, 0, 0};
        }
    float bu[8];
    #pragma unroll
    for (int c = 0; c < 8; ++c) bu[c] = upB[c * 16 + ccol];

    // GEMM1: s1 = relu(sbf @ W1), K=96
    {
        short8 a0[3], a1[3];
        #pragma unroll
        for (int kb = 0; kb < 3; ++kb) {
            a0[kb] = *(const short8*)&lds[sidx(ar0, kb * 64 + kgrp * 16)];
            a1[kb] = *(const short8*)&lds[sidx(ar1, kb * 64 + kgrp * 16)];
        }
        colmm8_dual<3, 96>(a0, a1, W1t + ccol * 96 + kgrp * 8,
            [&](int c, floatx4 A0, floatx4 A1) {
                int bc = 2 * (c * 16 + ccol);
                #pragma unroll
                for (int j = 0; j < 4; ++j) {
                    lds[sidx(cb0 + j, bc)] = f2bf(fmaxf(A0[j], 0.f));
                    lds[sidx(cb1 + j, bc)] = f2bf(fmaxf(A1[j], 0.f));
                }
            });
    }

    // GEMM2: x = relu(s1 @ W2) * xd, K=128
    {
        short8 a0[4], a1[4];
        #pragma unroll
        for (int kb = 0; kb < 4; ++kb) {
            a0[kb] = *(const short8*)&lds[sidx(ar0, kb * 64 + kgrp * 16)];
            a1[kb] = *(const short8*)&lds[sidx(ar1, kb * 64 + kgrp * 16)];
        }
        colmm8_dual<4, 128>(a0, a1, W2t + ccol * 128 + kgrp * 8,
            [&](int c, floatx4 A0, floatx4 A1) {
                int bc = 2 * (c * 16 + ccol);
                #pragma unroll
                for (int j = 0; j < 4; ++j) {
                    lds[sidx(cb0 + j, bc)] = f2bf(fmaxf(A0[j], 0.f) * bf2f(xds[0][j][c]));
                    lds[sidx(cb1 + j, bc)] = f2bf(fmaxf(A1[j], 0.f) * bf2f(xds[1][j][c]));
                }
            });
    }

    // GEMM3: y = relu(x @ W3 + b) -> ysort rows (per-col accumulate into short8, store after)
    {
        short8 a0[4], a1[4];
        #pragma unroll
        for (int kb = 0; kb < 4; ++kb) {
            a0[kb] = *(const short8*)&lds[sidx(ar0, kb * 64 + kgrp * 16)];
            a1[kb] = *(const short8*)&lds[sidx(ar1, kb * 64 + kgrp * 16)];
        }
        short8 y0[4], y1[4];
        colmm8_dual<4, 128>(a0, a1, W3t + ccol * 128 + kgrp * 8,
            [&](int c, floatx4 A0, floatx4 A1) {
                #pragma unroll
                for (int j = 0; j < 4; ++j) {
                    y0[j][c] = f2bf(fmaxf(A0[j] + bu[c], 0.f));
                    y1[j][c] = f2bf(fmaxf(A1[j] + bu[c], 0.f));
                }
            });
        #pragma unroll
        for (int j = 0; j < 4; ++j) {
            int r0r = row0 + cb0 + j;
            int r1r = row0 + cb1 + j;
            if (r0r < Tcnt) *(short8*)&ysort[(size_t)r0r * 128 + ccol * 8] = y0[j];
            if (r1r < Tcnt) *(short8*)&ysort[(size_t)r1r * 128 + ccol * 8] = y1[j];
        }
    }
}

// ---------------- fused layerB: CSR segment-sum + res-MLP + msg update ----------------
__launch_bounds__(256)
__global__ void layerBf_k(const short* __restrict__ ysort, const int* __restrict__ sstart,
                          const short* __restrict__ r1Wt, const float* __restrict__ r1B,
                          const short* __restrict__ r2Wt, const float* __restrict__ r2B,
                          float* __restrict__ msg) {
    __shared__ short ldsb[64 * 128];
    __shared__ float aggf[64 * 128];
    const int tid = threadIdx.x;
    const int lane = tid & 63, w = tid >> 6;
    const int row0 = blockIdx.x * 64;
    const int g16 = lane & 15;
    const int q   = lane >> 4;

    for (int it = 0; it < 16; ++it) {
        int el = it * 4 + w;
        int e = row0 + el;
        int s = sstart[e], tEnd = sstart[e + 1];
        float acc[8] = {0.f, 0.f, 0.f, 0.f, 0.f, 0.f, 0.f, 0.f};
        for (int r = s + q; r < tEnd; r += 4) {
            short8 y = *(const short8*)&ysort[(size_t)r * 128 + g16 * 8];
            #pragma unroll
            for (int c = 0; c < 8; ++c) acc[c] += bf2f(y[c]);
        }
        #pragma unroll
        for (int c = 0; c < 8; ++c) {
            acc[c] += __shfl_xor(acc[c], 16);
            acc[c] += __shfl_xor(acc[c], 32);
        }
        if (q == 0) {
            unsigned u[4];
            #pragma unroll
            for (int h = 0; h < 4; ++h) u[h] = pack2(acc[2 * h], acc[2 * h + 1]);
            *(uint4*)&ldsb[sidx(el, g16 * 16)] = make_uint4(u[0], u[1], u[2], u[3]);
            *(float4*)&aggf[el * 128 + g16 * 8]     = make_float4(acc[0], acc[1], acc[2], acc[3]);
            *(float4*)&aggf[el * 128 + g16 * 8 + 4] = make_float4(acc[4], acc[5], acc[6], acc[7]);
        }
    }
    __syncthreads();

    const int kgrp = lane >> 4, ccol = lane & 15;
    const int arow = w * 16 + ccol;
    const int cr0  = w * 16 + kgrp * 4;
    short8 a1[4];
    #pragma unroll
    for (int kb = 0; kb < 4; ++kb)
        a1[kb] = *(const short8*)&ldsb[sidx(arow, kb * 64 + kgrp * 16)];
    floatx4 o[8];
    colmm8_pf<4, 128>(a1, r1Wt + ccol * 128 + kgrp * 8, o);
    #pragma unroll
    for (int c = 0; c < 8; ++c) {
        int colg = c * 16 + ccol;
        float b1 = r1B[colg];
        #pragma unroll
        for (int j = 0; j < 4; ++j)
            ldsb[sidx(cr0 + j, 2 * colg)] = f2bf(fmaxf(o[c][j] + b1, 0.f));
    }
    short8 a2[4];
    #pragma unroll
    for (int kb = 0; kb < 4; ++kb)
        a2[kb] = *(const short8*)&ldsb[sidx(arow, kb * 64 + kgrp * 16)];
    colmm8_pf<4, 128>(a2, r2Wt + ccol * 128 + kgrp * 8, o);
    #pragma unroll
    for (int c = 0; c < 8; ++c) {
        int colg = c * 16 + ccol;
        float b2 = r2B[colg];
        #pragma unroll
        for (int j = 0; j < 4; ++j) {
            size_t ofs = (size_t)(row0 + cr0 + j) * 128 + colg;
            float ag = aggf[(cr0 + j) * 128 + ccol * 8 + c];
            msg[ofs] = msg[ofs] + ag + fmaxf(o[c][j] + b2, 0.f);
        }
    }
}

// ---------------- initial message (K=160, pad 147) ----------------
__launch_bounds__(256, 3)
__global__ void imsg_k(const float* __restrict__ af, const float* __restrict__ ef,
                       const int* __restrict__ idx_j,
                       const short* __restrict__ Wt, const float* __restrict__ bias,
                       float* __restrict__ msg) {
    __shared__ short lds[64 * 256];
    const int tid = threadIdx.x;
    const int lane = tid & 63, w = tid >> 6;
    const int row0 = blockIdx.x * 64;

    #pragma unroll
    for (int it = 0; it < 5; ++it) {
        int chunk = tid + it * 256;
        int r = chunk / 20, cg = chunk % 20;
        int row = row0 + r;
        int g = idx_j[row];
        unsigned u[4];
        #pragma unroll
        for (int h = 0; h < 4; ++h) {
            int k0 = cg * 8 + 2 * h;
            int k1 = k0 + 1;
            float f0 = (k0 < 133) ? af[(size_t)g * 133 + k0]
                     : (k0 < 147) ? ef[(size_t)row * 14 + (k0 - 133)] : 0.f;
            float f1 = (k1 < 133) ? af[(size_t)g * 133 + k1]
                     : (k1 < 147) ? ef[(size_t)row * 14 + (k1 - 133)] : 0.f;
            u[h] = pack2(f0, f1);
        }
        *(uint4*)&lds[sidxg(r, cg * 16, 256)] = make_uint4(u[0], u[1], u[2], u[3]);
    }
    __syncthreads();

    const int kgrp = lane >> 4, ccol = lane & 15;
    const int arow = w * 16 + ccol;
    const int cr0  = w * 16 + kgrp * 4;
    short8 a[5];
    #pragma unroll
    for (int kb = 0; kb < 5; ++kb)
        a[kb] = *(const short8*)&lds[sidxg(arow, kb * 64 + kgrp * 16, 256)];
    floatx4 o[8];
    colmm8_pf<5, 160>(a, Wt + ccol * 160 + kgrp * 8, o);
    #pragma unroll
    for (int c = 0; c < 8; ++c) {
        int colg = c * 16 + ccol;
        float bv = bias[colg];
        #pragma unroll
        for (int j = 0; j < 4; ++j)
            msg[(size_t)(row0 + cr0 + j) * 128 + colg] = fmaxf(o[c][j] + bv, 0.f);
    }
}

// ---------------- layerA ----------------
__launch_bounds__(256, 3)
__global__ void layerA_k(const float* __restrict__ msg, const short* __restrict__ rbfe,
                         const short* __restrict__ kjWt, const float* __restrict__ kjB,
                         const short* __restrict__ rbf2Wt, const float* __restrict__ rbf2B,
                         const short* __restrict__ downWt, const float* __restrict__ downB,
                         short* __restrict__ xdown) {
    __shared__ short ldsM[64 * 128];
    __shared__ short ldsR[64 * 128];
    const int tid = threadIdx.x;
    const int lane = tid & 63, w = tid >> 6;
    const size_t row0 = (size_t)blockIdx.x * 64;
    stage64x128(msg, row0, ldsM, tid);
    stage_bf(rbfe, row0, ldsR, tid);
    __syncthreads();
    const int kgrp = lane >> 4, ccol = lane & 15;
    const int arow = w * 16 + ccol;
    const int cr0  = w * 16 + kgrp * 4;
    short8 aM[4], aR[4];
    #pragma unroll
    for (int kb = 0; kb < 4; ++kb) {
        aM[kb] = *(const short8*)&ldsM[sidx(arow, kb * 64 + kgrp * 16)];
        aR[kb] = *(const short8*)&ldsR[sidx(arow, kb * 64 + kgrp * 16)];
    }
    floatx4 oR[8], oK[8];
    colmm8_pf<4, 128>(aR, rbf2Wt + ccol * 128 + kgrp * 8, oR);
    colmm8_pf<4, 128>(aM, kjWt   + ccol * 128 + kgrp * 8, oK);
    #pragma unroll
    for (int c = 0; c < 8; ++c) {
        int colg = c * 16 + ccol;
        float rb = rbf2B[colg], kbb = kjB[colg];
        #pragma unroll
        for (int j = 0; j < 4; ++j) {
            float x = fmaxf(oK[c][j] + kbb, 0.f) * fmaxf(oR[c][j] + rb, 0.f);
            ldsM[sidx(cr0 + j, 2 * colg)] = f2bf(x);
        }
    }
    short8 aX[4];
    #pragma unroll
    for (int kb = 0; kb < 4; ++kb)
        aX[kb] = *(const short8*)&ldsM[sidx(arow, kb * 64 + kgrp * 16)];
    colmm8_pf<4, 128>(aX, downWt + ccol * 128 + kgrp * 8, oK);
    #pragma unroll
    for (int j = 0; j < 4; ++j) {
        short8 v;
        #pragma unroll
        for (int c = 0; c < 8; ++c)
            v[c] = f2bf(fmaxf(oK[c][j] + downB[c * 16 + ccol], 0.f));
        *(short8*)&xdown[(row0 + cr0 + j) * 128 + ccol * 8] = v;
    }
}

// ---------------- rbfe (bf16 out) ----------------
__launch_bounds__(256, 3)
__global__ void rbfe_k(const float* __restrict__ rbfh, const short* __restrict__ W3t,
                       const float* __restrict__ bias,
                       const int* __restrict__ idx_i, const int* __restrict__ idx_j,
                       const int* __restrict__ atype,
                       const float* __restrict__ P1, const float* __restrict__ P2,
                       short* __restrict__ out) {
    __shared__ short lds[64 * 128];
    const int tid = threadIdx.x;
    const int lane = tid & 63, w = tid >> 6;
    const size_t row0 = (size_t)blockIdx.x * 64;
    stage64x128(rbfh, row0, lds, tid);
    const int kgrp = lane >> 4, ccol = lane & 15;
    const int arow = w * 16 + ccol;
    const int cr0  = w * 16 + kgrp * 4;
    const float* p1p[4]; const float* p2p[4];
    #pragma unroll
    for (int j = 0; j < 4; ++j) {
        size_t row = row0 + cr0 + j;
        p1p[j] = P1 + (size_t)atype[idx_i[row]] * 128;
        p2p[j] = P2 + (size_t)atype[idx_j[row]] * 128;
    }
    __syncthreads();
    short8 a[4];
    #pragma unroll
    for (int kb = 0; kb < 4; ++kb)
        a[kb] = *(const short8*)&lds[sidx(arow, kb * 64 + kgrp * 16)];
    floatx4 o[8];
    colmm8_pf<4, 128>(a, W3t + ccol * 128 + kgrp * 8, o);
    #pragma unroll
    for (int c = 0; c < 8; ++c) {
        int colg = c * 16 + ccol;
        float bv = bias[colg];
        #pragma unroll
        for (int j = 0; j < 4; ++j)
            out[(row0 + cr0 + j) * 128 + colg] =
                f2bf(fmaxf(o[c][j] + bv + p1p[j][colg] + p2p[j][colg], 0.f));
    }
}

// ---------------- concat GEMM (fp32, final projection only) ----------------
__launch_bounds__(256)
__global__ void concatgemm_k(const float* __restrict__ IN1, int K1,
                             const float* __restrict__ IN2, int K2,
                             const float* __restrict__ W, const float* __restrict__ bias,
                             float* __restrict__ Y, int M) {
    __shared__ float xs[96 * 68];
    const int tid = threadIdx.x;
    const int row0 = blockIdx.x * 64;
    const int col8 = (tid & 15) * 8;
    const int r0 = (tid >> 4) * 4;
    const int K = K1 + K2;

    float acc[4][8];
    #pragma unroll
    for (int r = 0; r < 4; ++r)
        #pragma unroll
        for (int c = 0; c < 8; ++c) acc[r][c] = 0.f;

    for (int kb = 0; kb < K; kb += 96) {
        int kc = (K - kb < 96) ? (K - kb) : 96;
        __syncthreads();
        for (int idx = tid; idx < 64 * 96; idx += 256) {
            int r = idx / 96, kl = idx % 96;
            if (kl < kc) {
                int row = row0 + r;
                float v = 0.f;
                if (row < M) {
                    int kg = kb + kl;
                    v = (kg < K1) ? IN1[(size_t)row * K1 + kg]
                                  : IN2[(size_t)row * K2 + (kg - K1)];
                }
                xs[kl * 68 + r] = v;
            }
        }
        __syncthreads();
        for (int k = 0; k < kc; ++k) {
            float4 xv = *(const float4*)&xs[k * 68 + r0];
            const float* wr = &W[(size_t)(kb + k) * 128 + col8];
            float4 w0 = *(const float4*)wr;
            float4 w1 = *(const float4*)(wr + 4);
            float xr[4] = {xv.x, xv.y, xv.z, xv.w};
            float wc[8] = {w0.x, w0.y, w0.z, w0.w, w1.x, w1.y, w1.z, w1.w};
            #pragma unroll
            for (int r = 0; r < 4; ++r)
                #pragma unroll
                for (int c = 0; c < 8; ++c)
                    acc[r][c] = fmaf(xr[r], wc[c], acc[r][c]);
        }
    }

    float4 b0 = *(const float4*)&bias[col8];
    float4 b1 = *(const float4*)&bias[col8 + 4];
    float bb[8] = {b0.x, b0.y, b0.z, b0.w, b1.x, b1.y, b1.z, b1.w};
    #pragma unroll
    for (int r = 0; r < 4; ++r) {
        int row = row0 + r0 + r;
        if (row >= M) continue;
        float v[8];
        #pragma unroll
        for (int c = 0; c < 8; ++c) v[c] = fmaxf(acc[r][c] + bb[c], 0.f);
        *(float4*)&Y[(size_t)row * 128 + col8]     = make_float4(v[0], v[1], v[2], v[3]);
        *(float4*)&Y[(size_t)row * 128 + col8 + 4] = make_float4(v[4], v[5], v[6], v[7]);
    }
}

// ---------------- host ----------------

extern "C" void kernel_launch(void* const* d_in, const int* in_sizes, int n_in,
                              void* d_out, int out_size, void* d_ws, size_t ws_size,
                              hipStream_t stream) {
    const float* atom_feature = (const float*)d_in[0];
    const float* edge_feature = (const float*)d_in[1];
    const float* dist         = (const float*)d_in[2];
    const float* angle        = (const float*)d_in[3];
    const float* W_i1_w       = (const float*)d_in[4];
    const float* W_i1_b       = (const float*)d_in[5];
    const float* emb_table    = (const float*)d_in[6];
    const float* lin_rbf_w    = (const float*)d_in[7];
    const float* lin_rbf_b    = (const float*)d_in[8];
    const float* lin_emb_w    = (const float*)d_in[9];
    const float* lin_emb_b    = (const float*)d_in[10];
    const float* bessel_freq  = (const float*)d_in[11];
    const float* L_rbf2_w     = (const float*)d_in[12];
    const float* L_rbf2_b     = (const float*)d_in[13];
    const float* L_kj_w       = (const float*)d_in[14];
    const float* L_kj_b       = (const float*)d_in[15];
    const float* L_sbf1_w     = (const float*)d_in[16];
    const float* L_sbf2_w     = (const float*)d_in[17];
    const float* L_down_w     = (const float*)d_in[18];
    const float* L_down_b     = (const float*)d_in[19];
    const float* L_up_w       = (const float*)d_in[20];
    const float* L_up_b       = (const float*)d_in[21];
    const float* L_res1_w     = (const float*)d_in[22];
    const float* L_res1_b     = (const float*)d_in[23];
    const float* L_res2_w     = (const float*)d_in[24];
    const float* L_res2_b     = (const float*)d_in[25];
    const float* W_o_w        = (const float*)d_in[26];
    const float* W_o_b        = (const float*)d_in[27];
    const int* idx_i          = (const int*)d_in[28];
    const int* idx_j          = (const int*)d_in[29];
    const int* idx_kj         = (const int*)d_in[30];
    const int* ib_eid         = (const int*)d_in[32];
    const int* ib_atom        = (const int*)d_in[33];

    float* ws = (float*)d_ws;
    size_t off = 0;
    auto take = [&](size_t n) { float* p = ws + off; off += n; return p; };
    float* msg   = take((size_t)Ecnt * 128);
    short* rbfe  = (short*)take((size_t)Ecnt * 64);
    short* sxd   = (short*)take((size_t)Ecnt * 64);
    short* ysort = (short*)take((size_t)Tcnt * 64);
    float* rbf0b = take((size_t)Ecnt * 16);
    float* P1    = take(100 * 128);
    float* P2    = take(100 * 128);
    int*   atyp  = (int*)take(Ncnt);
    int*   cnts  = (int*)take(Ecnt);
    int*   sstart= (int*)take(Ecnt + 1);
    int*   cur   = (int*)take(Ecnt);
    int*   btot  = (int*)take(512);
    int*   boff  = (int*)take(512);
    int*   eids  = (int*)take(Tcnt);
    float* angs  = take(Tcnt);
    short* wts   = (short*)take(160000);

    if (off * sizeof(float) > ws_size) {
        sentinel_k<<<1, 256, 0, stream>>>((float*)d_out, (float)ws_size);
        return;
    }

    float* rbfh_s = (float*)ysort;
    float* atomm  = (float*)ysort;

    const int GE  = Ecnt / 64;
    const int GN  = (Ncnt + 63) / 64;
    const int GT  = (Tcnt + 127) / 128;    // 3907 (128-row tiles)
    const int NBE = (Ecnt + 255) / 256;
    const int NBT = (Tcnt + 255) / 256;

    atype_k<<<(Ncnt + 255) / 256, 256, 0, stream>>>(atom_feature, atyp);
    pemb_k<<<100, 128, 0, stream>>>(emb_table, lin_emb_w, P1, P2);
    rbf0_k<<<NBE, 256, 0, stream>>>(dist, bessel_freq, rbf0b);

    hipMemsetAsync(cnts, 0, (size_t)Ecnt * sizeof(int), stream);
    hist_k<<<NBT, 256, 0, stream>>>(idx_kj, cnts);
    scan1_k<<<NBE, 256, 0, stream>>>(cnts, btot);
    scan2_k<<<1, 512, 0, stream>>>(btot, boff, NBE);
    scan3_k<<<NBE, 256, 0, stream>>>(cnts, boff, sstart, cur);
    perm_k<<<NBT, 256, 0, stream>>>(idx_kj, angle, cur, eids, angs);

    short* p = wts;
    short* wt1[2]; short* wt2[2]; short* wt3[2];
    short* wkj[2]; short* wr2f[2]; short* wdn[2]; short* wr1[2]; short* wr2[2];
    for (int l = 0; l < 2; ++l) {
        wt1[l] = p; p += 96 * 128;
        wt2[l] = p; p += 128 * 128;
        wt3[l] = p; p += 128 * 128;
        wkj[l] = p; p += 128 * 128;
        wr2f[l] = p; p += 128 * 128;
        wdn[l] = p; p += 128 * 128;
        wr1[l] = p; p += 128 * 128;
        wr2[l] = p; p += 128 * 128;
    }
    short* wemb3 = p; p += 128 * 128;
    short* wi1t  = p; p += 128 * 160;

    WPack wp;
    int m = 0;
    for (int l = 0; l < 2; ++l) {
        wp.src[m] = L_sbf2_w + (size_t)l * 128 * 128; wp.dst[m++] = wt2[l];
        wp.src[m] = L_up_w   + (size_t)l * 128 * 128; wp.dst[m++] = wt3[l];
        wp.src[m] = L_kj_w   + (size_t)l * 128 * 128; wp.dst[m++] = wkj[l];
        wp.src[m] = L_rbf2_w + (size_t)l * 128 * 128; wp.dst[m++] = wr2f[l];
        wp.src[m] = L_down_w + (size_t)l * 128 * 128; wp.dst[m++] = wdn[l];
        wp.src[m] = L_res2_w + (size_t)l * 128 * 128; wp.dst[m++] = wr2[l];
    }
    wp.src[m] = lin_emb_w + 256 * 128; wp.dst[m++] = wemb3;   // m == 13
    transmany_k<<<13 * 64, 256, 0, stream>>>(wp);
    const int G96 = (96 * 128 + 255) / 256, G128 = (128 * 128 + 255) / 256;
    transcvt_k<<<G96, 256, 0, stream>>>(L_sbf1_w, wt1[0], 96);
    transcvt_k<<<G96, 256, 0, stream>>>(L_sbf1_w + (size_t)96 * 128, wt1[1], 96);
    transperm_k<<<G128, 256, 0, stream>>>(L_res1_w, wr1[0]);
    transperm_k<<<G128, 256, 0, stream>>>(L_res1_w + (size_t)128 * 128, wr1[1]);
    transWi1_k<<<(128 * 160 + 255) / 256, 256, 0, stream>>>(W_i1_w, wi1t);

    imsg_k<<<GE, 256, 0, stream>>>(atom_feature, edge_feature, idx_j, wi1t, W_i1_b, msg);
    rbfh_k<<<(Ecnt * 128) / 256, 256, 0, stream>>>(rbf0b, lin_rbf_w, lin_rbf_b, rbfh_s);
    rbfe_k<<<GE, 256, 0, stream>>>(rbfh_s, wemb3, lin_emb_b, idx_i, idx_j, atyp, P1, P2, rbfe);

    for (int l = 0; l < 2; ++l) {
        layerA_k<<<GE, 256, 0, stream>>>(msg, rbfe,
                                         wkj[l], L_kj_b + (size_t)l * 128,
                                         wr2f[l], L_rbf2_b + (size_t)l * 128,
                                         wdn[l], L_down_b + (size_t)l * 128, sxd);
        triplet_mfma_k<<<GT, 256, 0, stream>>>(angs, eids, rbf0b,
                                               wt1[l], wt2[l], wt3[l],
                                               L_up_b + (size_t)l * 128, sxd, ysort);
        layerBf_k<<<GE, 256, 0, stream>>>(ysort, sstart,
                                          wr1[l], L_res1_b + (size_t)l * 128,
                                          wr2[l], L_res2_b + (size_t)l * 128, msg);
    }

    hipMemsetAsync(atomm, 0, (size_t)Ncnt * 128 * sizeof(float), stream);
    scatatom_k<<<(Ecnt * 128) / 256, 256, 0, stream>>>(msg, ib_eid, ib_atom, atomm);
    concatgemm_k<<<GN, 256, 0, stream>>>(atom_feature, 133, atomm, 128,
                                         W_o_w, W_o_b, (float*)d_out, Ncnt);
}

// Round 10
// 1136.392 us; speedup vs baseline: 1.2706x; 1.1544x over previous
//
#include <hip/hip_runtime.h>
#include <hip/hip_bf16.h>

#define Ecnt 120000
#define Ncnt 15000
#define Tcnt 500000
#define NT128 ((Tcnt + 127) / 128)

typedef __attribute__((ext_vector_type(8))) short short8;
typedef __attribute__((ext_vector_type(4))) float floatx4;

__device__ __forceinline__ floatx4 mfma16(short8 a, short8 b, floatx4 c) {
    return __builtin_amdgcn_mfma_f32_16x16x32_bf16(a, b, c, 0, 0, 0);
}

__device__ __forceinline__ short f2bf(float f) {
    __hip_bfloat16 b = __float2bfloat16(f);
    short s;
    __builtin_memcpy(&s, &b, 2);
    return s;
}

__device__ __forceinline__ float bf2f(short s) {
    unsigned u = ((unsigned)(unsigned short)s) << 16;
    float f;
    __builtin_memcpy(&f, &u, 4);
    return f;
}

__device__ __forceinline__ unsigned pack2(float x, float y) {
    return (unsigned)(unsigned short)f2bf(x) | ((unsigned)(unsigned short)f2bf(y) << 16);
}

// bf16 MFMA tile swizzle: byte-col XOR (row&15)<<4, BOTH sides, bijective in
// 256B-aligned windows (128-short rows ok; 256-short rows ok for bc<=304).
__device__ __forceinline__ int sidx(int row, int bc) {
    return row * 128 + (((bc) ^ ((row & 15) << 4)) >> 1);
}
__device__ __forceinline__ int sidxg(int row, int bc, int ldshorts) {
    return row * ldshorts + (((bc) ^ ((row & 15) << 4)) >> 1);
}

__device__ __forceinline__ void stage64x128(const float* __restrict__ src, size_t row0,
                                            short* __restrict__ lds, int tid) {
    #pragma unroll
    for (int it = 0; it < 8; ++it) {
        int chunk = tid + it * 256;
        int r = chunk >> 5, c4 = chunk & 31;
        float4 v = *(const float4*)&src[(row0 + r) * 128 + c4 * 4];
        *(uint2*)&lds[sidx(r, c4 * 8)] = make_uint2(pack2(v.x, v.y), pack2(v.z, v.w));
    }
}

__device__ __forceinline__ void stage_bf(const short* __restrict__ src, size_t row0,
                                         short* __restrict__ lds, int tid) {
    #pragma unroll
    for (int it = 0; it < 4; ++it) {
        int chunk = tid + it * 256;
        int r = chunk >> 4, cg = chunk & 15;
        uint4 v = *(const uint4*)&src[(row0 + r) * 128 + cg * 8];
        *(uint4*)&lds[sidx(r, cg * 16)] = v;
    }
}

// 8-column-tile GEMM, weights from GLOBAL (L2), 2-deep prefetch (E-path kernels)
template<int NKB, int K>
__device__ __forceinline__ void colmm8_pf(const short8 a[NKB], const short* __restrict__ wcol,
                                          floatx4 out[8]) {
    short8 w[2][NKB];
    #pragma unroll
    for (int kb = 0; kb < NKB; ++kb) w[0][kb] = *(const short8*)(wcol + kb * 32);
    #pragma unroll
    for (int kb = 0; kb < NKB; ++kb) w[1][kb] = *(const short8*)(wcol + 16 * K + kb * 32);
    #pragma unroll
    for (int c = 0; c < 8; ++c) {
        floatx4 acc = {0.f, 0.f, 0.f, 0.f};
        #pragma unroll
        for (int kb = 0; kb < NKB; ++kb) acc = mfma16(a[kb], w[c & 1][kb], acc);
        out[c] = acc;
        if (c + 2 < 8) {
            #pragma unroll
            for (int kb = 0; kb < NKB; ++kb)
                w[c & 1][kb] = *(const short8*)(wcol + (size_t)(c + 2) * 16 * K + kb * 32);
        }
    }
}

// 8-column-tile GEMM, weights from LDS fragment-major array.
// wf = wlds + lane*8; fragment (c,kb) at wf + (c*NKB+kb)*512 — each wave read is
// a contiguous 1KB ds_read_b128 burst (conflict-free).
template<int NKB>
__device__ __forceinline__ void colmm8_lds(const short8 a[NKB], const short* __restrict__ wf,
                                           floatx4 out[8]) {
    short8 w[2][NKB];
    #pragma unroll
    for (int kb = 0; kb < NKB; ++kb) w[0][kb] = *(const short8*)(wf + kb * 512);
    #pragma unroll
    for (int kb = 0; kb < NKB; ++kb) w[1][kb] = *(const short8*)(wf + (NKB + kb) * 512);
    #pragma unroll
    for (int c = 0; c < 8; ++c) {
        floatx4 acc = {0.f, 0.f, 0.f, 0.f};
        #pragma unroll
        for (int kb = 0; kb < NKB; ++kb) acc = mfma16(a[kb], w[c & 1][kb], acc);
        out[c] = acc;
        if (c + 2 < 8) {
            #pragma unroll
            for (int kb = 0; kb < NKB; ++kb)
                w[c & 1][kb] = *(const short8*)(wf + ((c + 2) * NKB + kb) * 512);
        }
    }
}

// ---------------- small kernels ----------------

__launch_bounds__(256)
__global__ void sentinel_k(float* o, float v) { o[0] = v; }

__launch_bounds__(256)
__global__ void atype_k(const float* __restrict__ af, int* __restrict__ atype) {
    int n = blockIdx.x * 256 + threadIdx.x;
    if (n >= Ncnt) return;
    const float* r = af + (size_t)n * 133;
    int best = 0; float bv = r[0];
    for (int k = 1; k < 100; ++k) { float v = r[k]; if (v > bv) { bv = v; best = k; } }
    atype[n] = best;
}

__launch_bounds__(128)
__global__ void pemb_k(const float* __restrict__ emb, const float* __restrict__ W,
                       float* __restrict__ P1, float* __restrict__ P2) {
    int r = blockIdx.x, c = threadIdx.x;
    __shared__ float er[128];
    er[c] = emb[r * 128 + c];
    __syncthreads();
    float a1 = 0.f, a2 = 0.f;
    for (int k = 0; k < 128; ++k) {
        float e = er[k];
        a1 = fmaf(e, W[k * 128 + c], a1);
        a2 = fmaf(e, W[(128 + k) * 128 + c], a2);
    }
    P1[r * 128 + c] = a1;
    P2[r * 128 + c] = a2;
}

__launch_bounds__(256)
__global__ void rbf0_k(const float* __restrict__ dist, const float* __restrict__ freq,
                       float* __restrict__ rbf0) {
    int e = blockIdx.x * 256 + threadIdx.x;
    if (e >= Ecnt) return;
    float x = dist[e] * 0.125f;
    float x2 = x * x;
    float x5 = x2 * x2 * x;
    float env = 1.f / x - 28.f * x5 + 48.f * x5 * x - 21.f * x5 * x2;
    if (!(x < 1.f)) env = 0.f;
    #pragma unroll
    for (int r = 0; r < 16; ++r)
        rbf0[(size_t)e * 16 + r] = env * sinf(freq[r] * x);
}

__launch_bounds__(256)
__global__ void rbfh_k(const float* __restrict__ rbf0, const float* __restrict__ W,
                       const float* __restrict__ bias, float* __restrict__ Y) {
    int gid = blockIdx.x * 256 + threadIdx.x;
    int e = gid >> 7, c = gid & 127;
    float acc = bias[c];
    #pragma unroll
    for (int k = 0; k < 16; ++k)
        acc = fmaf(rbf0[(size_t)e * 16 + k], W[k * 128 + c], acc);
    Y[(size_t)e * 128 + c] = fmaxf(acc, 0.f);
}

__launch_bounds__(256)
__global__ void scatatom_k(const float* __restrict__ msg, const int* __restrict__ eid,
                           const int* __restrict__ aid, float* __restrict__ am) {
    int gid = blockIdx.x * 256 + threadIdx.x;
    int e = gid >> 7, c = gid & 127;
    float v = msg[(size_t)eid[e] * 128 + c];
    atomicAdd(&am[(size_t)aid[e] * 128 + c], v);
}

// ---------------- sorting (CSR by target edge) ----------------

__launch_bounds__(256)
__global__ void hist_k(const int* __restrict__ idx, int* __restrict__ cnt) {
    int t = blockIdx.x * 256 + threadIdx.x;
    if (t < Tcnt) atomicAdd(&cnt[idx[t]], 1);
}

__launch_bounds__(256)
__global__ void scan1_k(int* __restrict__ cnt, int* __restrict__ btot) {
    __shared__ int s[256];
    int t = threadIdx.x, i = blockIdx.x * 256 + t;
    int v = (i < Ecnt) ? cnt[i] : 0;
    s[t] = v;
    #pragma unroll
    for (int off = 1; off < 256; off <<= 1) {
        __syncthreads();
        int nv = (t >= off) ? s[t - off] + s[t] : s[t];
        __syncthreads();
        s[t] = nv;
    }
    if (i < Ecnt) cnt[i] = s[t] - v;
    if (t == 255) btot[blockIdx.x] = s[255];
}

__launch_bounds__(512)
__global__ void scan2_k(const int* __restrict__ btot, int* __restrict__ boff, int nb) {
    __shared__ int s[512];
    int t = threadIdx.x;
    int v = (t < nb) ? btot[t] : 0;
    s[t] = v;
    #pragma unroll
    for (int off = 1; off < 512; off <<= 1) {
        __syncthreads();
        int nv = (t >= off) ? s[t - off] + s[t] : s[t];
        __syncthreads();
        s[t] = nv;
    }
    if (t < nb) boff[t] = s[t] - v;
}

__launch_bounds__(256)
__global__ void scan3_k(const int* __restrict__ basep, const int* __restrict__ boff,
                        int* __restrict__ sstart, int* __restrict__ cur) {
    int i = blockIdx.x * 256 + threadIdx.x;
    if (i < Ecnt) {
        int v = basep[i] + boff[i >> 8];
        sstart[i] = v;
        cur[i] = v;
    }
    if (i == 0) sstart[Ecnt] = Tcnt;
}

__launch_bounds__(256)
__global__ void perm_k(const int* __restrict__ idx, const float* __restrict__ angle,
                       int* __restrict__ cur, int* __restrict__ eids,
                       float* __restrict__ angs) {
    int t = blockIdx.x * 256 + threadIdx.x;
    if (t >= Tcnt) return;
    int e = idx[t];
    int p = atomicAdd(&cur[e], 1);
    eids[p] = e;
    angs[p] = angle[t];
}

// ---------------- weight conversion ----------------

struct WPack {
    const float* src[15];
    short* dst[15];
};
__launch_bounds__(256)
__global__ void transmany_k(WPack p) {
    int m = blockIdx.x >> 6;
    int i = ((blockIdx.x & 63) << 8) + threadIdx.x;
    int k = i >> 7, c = i & 127;
    p.dst[m][c * 128 + k] = f2bf(p.src[m][k * 128 + c]);
}

// fragment-major layout for LDS-resident weights:
// out[((c*NKB + kb)*64 + lane)*8 + e] = W[k][n], n = c*16 + (lane&15),
// k = kb*32 + (lane>>4)*8 + e.   (K = NKB*32)
__launch_bounds__(256)
__global__ void transfrag_k(const float* __restrict__ W, short* __restrict__ out, int NKB) {
    int i = blockIdx.x * 256 + threadIdx.x;
    if (i >= NKB * 4096) return;
    int e = i & 7;
    int lane = (i >> 3) & 63;
    int ckb = i >> 9;
    int c = ckb / NKB, kb = ckb - c * NKB;
    int n = c * 16 + (lane & 15);
    int k = kb * 32 + (lane >> 4) * 8 + e;
    out[i] = f2bf(W[(size_t)k * 128 + n]);
}

// r1 weight: K-index permuted by sigma(p) = (p&7)*16 + (p>>3) (ysort col order)
__launch_bounds__(256)
__global__ void transperm_k(const float* __restrict__ W, short* __restrict__ out) {
    int i = blockIdx.x * 256 + threadIdx.x;
    if (i >= 128 * 128) return;
    int n = i >> 7, p = i & 127;
    int k = (p & 7) * 16 + (p >> 3);
    out[i] = f2bf(W[k * 128 + n]);
}

__launch_bounds__(256)
__global__ void transWi1_k(const float* __restrict__ W, short* __restrict__ out) {
    int i = blockIdx.x * 256 + threadIdx.x;
    if (i >= 128 * 160) return;
    int c = i / 160, k = i % 160;
    out[i] = (k < 147) ? f2bf(W[k * 128 + c]) : (short)0;
}

// ---------------- triplet path: persistent, ALL WEIGHTS IN LDS ----------------
// 512 threads (8 waves), 120KB LDS: W1(24K)+W2(32K)+W3(32K) fragment-major +
// 128-row data tile (32K). Weights loaded once per block; tile loop is
// barrier-free (each wave owns rows [w*16, w*16+16) of the data tile).
__launch_bounds__(512)
__global__ void triplet_mfma_k(const float* __restrict__ angs, const int* __restrict__ eids,
                               const float* __restrict__ rbf0,
                               const short* __restrict__ W1f, const short* __restrict__ W2f,
                               const short* __restrict__ W3f, const float* __restrict__ upB,
                               const short* __restrict__ xdown, short* __restrict__ ysort) {
    __shared__ short wl[61440];          // 120 KB
    short* w1  = wl;                     // 12288 shorts (96x128, frag-major)
    short* w2  = wl + 12288;             // 16384
    short* w3  = wl + 28672;             // 16384
    short* dat = wl + 45056;             // 16384 (128-row swizzled data tile)

    const int tid = threadIdx.x;
    const int lane = tid & 63;
    const int w = tid >> 6;
    const int kgrp = lane >> 4;
    const int ccol = lane & 15;
    const int arow = w * 16 + ccol;       // this lane's A-row (tile-local)
    const int cr0  = w * 16 + kgrp * 4;   // this lane's C-rows

    // cooperative weight load (linear 16B copies), once per block
    for (int i = tid; i < 1536; i += 512)
        *(uint4*)&w1[i * 8] = *(const uint4*)&W1f[i * 8];
    for (int i = tid; i < 2048; i += 512)
        *(uint4*)&w2[i * 8] = *(const uint4*)&W2f[i * 8];
    for (int i = tid; i < 2048; i += 512)
        *(uint4*)&w3[i * 8] = *(const uint4*)&W3f[i * 8];
    __syncthreads();

    float bu[8];
    #pragma unroll
    for (int c = 0; c < 8; ++c) bu[c] = upB[c * 16 + ccol];
    const short* wf1 = w1 + lane * 8;
    const short* wf2 = w2 + lane * 8;
    const short* wf3 = w3 + lane * 8;

    for (int tile = blockIdx.x; tile < NT128; tile += gridDim.x) {
        const int row0 = tile * 128;

        // wave-local sbf staging: lane stages quarter kgrp of row arow
        {
            int srow = row0 + arow;
            float cb[6], rb[16];
            if (srow < Tcnt) {
                float ang = angs[srow];
                int ge = eids[srow];
                float c1 = cosf(ang);
                cb[0] = 1.f; cb[1] = c1;
                #pragma unroll
                for (int a = 2; a < 6; ++a) cb[a] = 2.f * c1 * cb[a - 1] - cb[a - 2];
                #pragma unroll
                for (int i4 = 0; i4 < 4; ++i4) {
                    float4 r4 = *(const float4*)&rbf0[(size_t)ge * 16 + i4 * 4];
                    rb[i4*4+0] = r4.x; rb[i4*4+1] = r4.y; rb[i4*4+2] = r4.z; rb[i4*4+3] = r4.w;
                }
            } else {
                #pragma unroll
                for (int a = 0; a < 6; ++a) cb[a] = 0.f;
                #pragma unroll
                for (int q = 0; q < 16; ++q) rb[q] = 0.f;
            }
            #pragma unroll
            for (int m = 0; m < 12; ++m) {
                int v0 = kgrp * 24 + 2 * m;
                *(unsigned*)&dat[sidx(arow, 2 * v0)] =
                    pack2(cb[v0 >> 4] * rb[v0 & 15], cb[(v0 + 1) >> 4] * rb[(v0 + 1) & 15]);
            }
        }

        int eidc[4];
        #pragma unroll
        for (int j = 0; j < 4; ++j) {
            int sr = row0 + cr0 + j;
            eidc[j] = (sr < Tcnt) ? eids[sr] : -1;
        }
        short8 xds[4];
        #pragma unroll
        for (int j = 0; j < 4; ++j) {
            if (eidc[j] >= 0)
                xds[j] = *(const short8*)&xdown[(size_t)eidc[j] * 128 + ccol * 8];
            else
                xds[j] = short8{0, 0, 0, 0, 0, 0, 0, 0};
        }

        floatx4 o[8];

        // GEMM1: s1 = relu(sbf @ W1), K=96
        {
            short8 a3[3];
            #pragma unroll
            for (int kb = 0; kb < 3; ++kb)
                a3[kb] = *(const short8*)&dat[sidx(arow, kb * 64 + kgrp * 16)];
            colmm8_lds<3>(a3, wf1, o);
            #pragma unroll
            for (int c = 0; c < 8; ++c)
                #pragma unroll
                for (int j = 0; j < 4; ++j)
                    dat[sidx(cr0 + j, 2 * (c * 16 + ccol))] = f2bf(fmaxf(o[c][j], 0.f));
        }

        // GEMM2: x = relu(s1 @ W2) * xd, K=128
        {
            short8 a4[4];
            #pragma unroll
            for (int kb = 0; kb < 4; ++kb)
                a4[kb] = *(const short8*)&dat[sidx(arow, kb * 64 + kgrp * 16)];
            colmm8_lds<4>(a4, wf2, o);
            #pragma unroll
            for (int c = 0; c < 8; ++c)
                #pragma unroll
                for (int j = 0; j < 4; ++j)
                    dat[sidx(cr0 + j, 2 * (c * 16 + ccol))] =
                        f2bf(fmaxf(o[c][j], 0.f) * bf2f(xds[j][c]));
        }

        // GEMM3: y = relu(x @ W3 + b) -> ysort (plain 16B stores)
        {
            short8 a4[4];
            #pragma unroll
            for (int kb = 0; kb < 4; ++kb)
                a4[kb] = *(const short8*)&dat[sidx(arow, kb * 64 + kgrp * 16)];
            colmm8_lds<4>(a4, wf3, o);
            short8 y[4];
            #pragma unroll
            for (int c = 0; c < 8; ++c)
                #pragma unroll
                for (int j = 0; j < 4; ++j)
                    y[j][c] = f2bf(fmaxf(o[c][j] + bu[c], 0.f));
            #pragma unroll
            for (int j = 0; j < 4; ++j) {
                int row = row0 + cr0 + j;
                if (row < Tcnt)
                    *(short8*)&ysort[(size_t)row * 128 + ccol * 8] = y[j];
            }
        }
    }
}

// ---------------- fused layerB: CSR segment-sum + res-MLP + msg update ----------------
__launch_bounds__(256)
__global__ void layerBf_k(const short* __restrict__ ysort, const int* __restrict__ sstart,
                          const short* __restrict__ r1Wt, const float* __restrict__ r1B,
                          const short* __restrict__ r2Wt, const float* __restrict__ r2B,
                          float* __restrict__ msg) {
    __shared__ short ldsb[64 * 128];
    __shared__ float aggf[64 * 128];
    const int tid = threadIdx.x;
    const int lane = tid & 63, w = tid >> 6;
    const int row0 = blockIdx.x * 64;
    const int g16 = lane & 15;
    const int q   = lane >> 4;

    for (int it = 0; it < 16; ++it) {
        int el = it * 4 + w;
        int e = row0 + el;
        int s = sstart[e], tEnd = sstart[e + 1];
        float acc[8] = {0.f, 0.f, 0.f, 0.f, 0.f, 0.f, 0.f, 0.f};
        for (int r = s + q; r < tEnd; r += 4) {
            short8 y = *(const short8*)&ysort[(size_t)r * 128 + g16 * 8];
            #pragma unroll
            for (int c = 0; c < 8; ++c) acc[c] += bf2f(y[c]);
        }
        #pragma unroll
        for (int c = 0; c < 8; ++c) {
            acc[c] += __shfl_xor(acc[c], 16);
            acc[c] += __shfl_xor(acc[c], 32);
        }
        if (q == 0) {
            unsigned u[4];
            #pragma unroll
            for (int h = 0; h < 4; ++h) u[h] = pack2(acc[2 * h], acc[2 * h + 1]);
            *(uint4*)&ldsb[sidx(el, g16 * 16)] = make_uint4(u[0], u[1], u[2], u[3]);
            *(float4*)&aggf[el * 128 + g16 * 8]     = make_float4(acc[0], acc[1], acc[2], acc[3]);
            *(float4*)&aggf[el * 128 + g16 * 8 + 4] = make_float4(acc[4], acc[5], acc[6], acc[7]);
        }
    }
    __syncthreads();

    const int kgrp = lane >> 4, ccol = lane & 15;
    const int arow = w * 16 + ccol;
    const int cr0  = w * 16 + kgrp * 4;
    short8 a1[4];
    #pragma unroll
    for (int kb = 0; kb < 4; ++kb)
        a1[kb] = *(const short8*)&ldsb[sidx(arow, kb * 64 + kgrp * 16)];
    floatx4 o[8];
    colmm8_pf<4, 128>(a1, r1Wt + ccol * 128 + kgrp * 8, o);
    #pragma unroll
    for (int c = 0; c < 8; ++c) {
        int colg = c * 16 + ccol;
        float b1 = r1B[colg];
        #pragma unroll
        for (int j = 0; j < 4; ++j)
            ldsb[sidx(cr0 + j, 2 * colg)] = f2bf(fmaxf(o[c][j] + b1, 0.f));
    }
    short8 a2[4];
    #pragma unroll
    for (int kb = 0; kb < 4; ++kb)
        a2[kb] = *(const short8*)&ldsb[sidx(arow, kb * 64 + kgrp * 16)];
    colmm8_pf<4, 128>(a2, r2Wt + ccol * 128 + kgrp * 8, o);
    #pragma unroll
    for (int c = 0; c < 8; ++c) {
        int colg = c * 16 + ccol;
        float b2 = r2B[colg];
        #pragma unroll
        for (int j = 0; j < 4; ++j) {
            size_t ofs = (size_t)(row0 + cr0 + j) * 128 + colg;
            float ag = aggf[(cr0 + j) * 128 + ccol * 8 + c];
            msg[ofs] = msg[ofs] + ag + fmaxf(o[c][j] + b2, 0.f);
        }
    }
}

// ---------------- initial message (K=160, pad 147) ----------------
__launch_bounds__(256, 3)
__global__ void imsg_k(const float* __restrict__ af, const float* __restrict__ ef,
                       const int* __restrict__ idx_j,
                       const short* __restrict__ Wt, const float* __restrict__ bias,
                       float* __restrict__ msg) {
    __shared__ short lds[64 * 256];
    const int tid = threadIdx.x;
    const int lane = tid & 63, w = tid >> 6;
    const int row0 = blockIdx.x * 64;

    #pragma unroll
    for (int it = 0; it < 5; ++it) {
        int chunk = tid + it * 256;
        int r = chunk / 20, cg = chunk % 20;
        int row = row0 + r;
        int g = idx_j[row];
        unsigned u[4];
        #pragma unroll
        for (int h = 0; h < 4; ++h) {
            int k0 = cg * 8 + 2 * h;
            int k1 = k0 + 1;
            float f0 = (k0 < 133) ? af[(size_t)g * 133 + k0]
                     : (k0 < 147) ? ef[(size_t)row * 14 + (k0 - 133)] : 0.f;
            float f1 = (k1 < 133) ? af[(size_t)g * 133 + k1]
                     : (k1 < 147) ? ef[(size_t)row * 14 + (k1 - 133)] : 0.f;
            u[h] = pack2(f0, f1);
        }
        *(uint4*)&lds[sidxg(r, cg * 16, 256)] = make_uint4(u[0], u[1], u[2], u[3]);
    }
    __syncthreads();

    const int kgrp = lane >> 4, ccol = lane & 15;
    const int arow = w * 16 + ccol;
    const int cr0  = w * 16 + kgrp * 4;
    short8 a[5];
    #pragma unroll
    for (int kb = 0; kb < 5; ++kb)
        a[kb] = *(const short8*)&lds[sidxg(arow, kb * 64 + kgrp * 16, 256)];
    floatx4 o[8];
    colmm8_pf<5, 160>(a, Wt + ccol * 160 + kgrp * 8, o);
    #pragma unroll
    for (int c = 0; c < 8; ++c) {
        int colg = c * 16 + ccol;
        float bv = bias[colg];
        #pragma unroll
        for (int j = 0; j < 4; ++j)
            msg[(size_t)(row0 + cr0 + j) * 128 + colg] = fmaxf(o[c][j] + bv, 0.f);
    }
}

// ---------------- layerA ----------------
__launch_bounds__(256, 3)
__global__ void layerA_k(const float* __restrict__ msg, const short* __restrict__ rbfe,
                         const short* __restrict__ kjWt, const float* __restrict__ kjB,
                         const short* __restrict__ rbf2Wt, const float* __restrict__ rbf2B,
                         const short* __restrict__ downWt, const float* __restrict__ downB,
                         short* __restrict__ xdown) {
    __shared__ short ldsM[64 * 128];
    __shared__ short ldsR[64 * 128];
    const int tid = threadIdx.x;
    const int lane = tid & 63, w = tid >> 6;
    const size_t row0 = (size_t)blockIdx.x * 64;
    stage64x128(msg, row0, ldsM, tid);
    stage_bf(rbfe, row0, ldsR, tid);
    __syncthreads();
    const int kgrp = lane >> 4, ccol = lane & 15;
    const int arow = w * 16 + ccol;
    const int cr0  = w * 16 + kgrp * 4;
    short8 aM[4], aR[4];
    #pragma unroll
    for (int kb = 0; kb < 4; ++kb) {
        aM[kb] = *(const short8*)&ldsM[sidx(arow, kb * 64 + kgrp * 16)];
        aR[kb] = *(const short8*)&ldsR[sidx(arow, kb * 64 + kgrp * 16)];
    }
    floatx4 oR[8], oK[8];
    colmm8_pf<4, 128>(aR, rbf2Wt + ccol * 128 + kgrp * 8, oR);
    colmm8_pf<4, 128>(aM, kjWt   + ccol * 128 + kgrp * 8, oK);
    #pragma unroll
    for (int c = 0; c < 8; ++c) {
        int colg = c * 16 + ccol;
        float rb = rbf2B[colg], kbb = kjB[colg];
        #pragma unroll
        for (int j = 0; j < 4; ++j) {
            float x = fmaxf(oK[c][j] + kbb, 0.f) * fmaxf(oR[c][j] + rb, 0.f);
            ldsM[sidx(cr0 + j, 2 * colg)] = f2bf(x);
        }
    }
    short8 aX[4];
    #pragma unroll
    for (int kb = 0; kb < 4; ++kb)
        aX[kb] = *(const short8*)&ldsM[sidx(arow, kb * 64 + kgrp * 16)];
    colmm8_pf<4, 128>(aX, downWt + ccol * 128 + kgrp * 8, oK);
    #pragma unroll
    for (int j = 0; j < 4; ++j) {
        short8 v;
        #pragma unroll
        for (int c = 0; c < 8; ++c)
            v[c] = f2bf(fmaxf(oK[c][j] + downB[c * 16 + ccol], 0.f));
        *(short8*)&xdown[(row0 + cr0 + j) * 128 + ccol * 8] = v;
    }
}

// ---------------- rbfe (bf16 out) ----------------
__launch_bounds__(256, 3)
__global__ void rbfe_k(const float* __restrict__ rbfh, const short* __restrict__ W3t,
                       const float* __restrict__ bias,
                       const int* __restrict__ idx_i, const int* __restrict__ idx_j,
                       const int* __restrict__ atype,
                       const float* __restrict__ P1, const float* __restrict__ P2,
                       short* __restrict__ out) {
    __shared__ short lds[64 * 128];
    const int tid = threadIdx.x;
    const int lane = tid & 63, w = tid >> 6;
    const size_t row0 = (size_t)blockIdx.x * 64;
    stage64x128(rbfh, row0, lds, tid);
    const int kgrp = lane >> 4, ccol = lane & 15;
    const int arow = w * 16 + ccol;
    const int cr0  = w * 16 + kgrp * 4;
    const float* p1p[4]; const float* p2p[4];
    #pragma unroll
    for (int j = 0; j < 4; ++j) {
        size_t row = row0 + cr0 + j;
        p1p[j] = P1 + (size_t)atype[idx_i[row]] * 128;
        p2p[j] = P2 + (size_t)atype[idx_j[row]] * 128;
    }
    __syncthreads();
    short8 a[4];
    #pragma unroll
    for (int kb = 0; kb < 4; ++kb)
        a[kb] = *(const short8*)&lds[sidx(arow, kb * 64 + kgrp * 16)];
    floatx4 o[8];
    colmm8_pf<4, 128>(a, W3t + ccol * 128 + kgrp * 8, o);
    #pragma unroll
    for (int c = 0; c < 8; ++c) {
        int colg = c * 16 + ccol;
        float bv = bias[colg];
        #pragma unroll
        for (int j = 0; j < 4; ++j)
            out[(row0 + cr0 + j) * 128 + colg] =
                f2bf(fmaxf(o[c][j] + bv + p1p[j][colg] + p2p[j][colg], 0.f));
    }
}

// ---------------- concat GEMM (fp32, final projection only) ----------------
__launch_bounds__(256)
__global__ void concatgemm_k(const float* __restrict__ IN1, int K1,
                             const float* __restrict__ IN2, int K2,
                             const float* __restrict__ W, const float* __restrict__ bias,
                             float* __restrict__ Y, int M) {
    __shared__ float xs[96 * 68];
    const int tid = threadIdx.x;
    const int row0 = blockIdx.x * 64;
    const int col8 = (tid & 15) * 8;
    const int r0 = (tid >> 4) * 4;
    const int K = K1 + K2;

    float acc[4][8];
    #pragma unroll
    for (int r = 0; r < 4; ++r)
        #pragma unroll
        for (int c = 0; c < 8; ++c) acc[r][c] = 0.f;

    for (int kb = 0; kb < K; kb += 96) {
        int kc = (K - kb < 96) ? (K - kb) : 96;
        __syncthreads();
        for (int idx = tid; idx < 64 * 96; idx += 256) {
            int r = idx / 96, kl = idx % 96;
            if (kl < kc) {
                int row = row0 + r;
                float v = 0.f;
                if (row < M) {
                    int kg = kb + kl;
                    v = (kg < K1) ? IN1[(size_t)row * K1 + kg]
                                  : IN2[(size_t)row * K2 + (kg - K1)];
                }
                xs[kl * 68 + r] = v;
            }
        }
        __syncthreads();
        for (int k = 0; k < kc; ++k) {
            float4 xv = *(const float4*)&xs[k * 68 + r0];
            const float* wr = &W[(size_t)(kb + k) * 128 + col8];
            float4 w0 = *(const float4*)wr;
            float4 w1 = *(const float4*)(wr + 4);
            float xr[4] = {xv.x, xv.y, xv.z, xv.w};
            float wc[8] = {w0.x, w0.y, w0.z, w0.w, w1.x, w1.y, w1.z, w1.w};
            #pragma unroll
            for (int r = 0; r < 4; ++r)
                #pragma unroll
                for (int c = 0; c < 8; ++c)
                    acc[r][c] = fmaf(xr[r], wc[c], acc[r][c]);
        }
    }

    float4 b0 = *(const float4*)&bias[col8];
    float4 b1 = *(const float4*)&bias[col8 + 4];
    float bb[8] = {b0.x, b0.y, b0.z, b0.w, b1.x, b1.y, b1.z, b1.w};
    #pragma unroll
    for (int r = 0; r < 4; ++r) {
        int row = row0 + r0 + r;
        if (row >= M) continue;
        float v[8];
        #pragma unroll
        for (int c = 0; c < 8; ++c) v[c] = fmaxf(acc[r][c] + bb[c], 0.f);
        *(float4*)&Y[(size_t)row * 128 + col8]     = make_float4(v[0], v[1], v[2], v[3]);
        *(float4*)&Y[(size_t)row * 128 + col8 + 4] = make_float4(v[4], v[5], v[6], v[7]);
    }
}

// ---------------- host ----------------

extern "C" void kernel_launch(void* const* d_in, const int* in_sizes, int n_in,
                              void* d_out, int out_size, void* d_ws, size_t ws_size,
                              hipStream_t stream) {
    const float* atom_feature = (const float*)d_in[0];
    const float* edge_feature = (const float*)d_in[1];
    const float* dist         = (const float*)d_in[2];
    const float* angle        = (const float*)d_in[3];
    const float* W_i1_w       = (const float*)d_in[4];
    const float* W_i1_b       = (const float*)d_in[5];
    const float* emb_table    = (const float*)d_in[6];
    const float* lin_rbf_w    = (const float*)d_in[7];
    const float* lin_rbf_b    = (const float*)d_in[8];
    const float* lin_emb_w    = (const float*)d_in[9];
    const float* lin_emb_b    = (const float*)d_in[10];
    const float* bessel_freq  = (const float*)d_in[11];
    const float* L_rbf2_w     = (const float*)d_in[12];
    const float* L_rbf2_b     = (const float*)d_in[13];
    const float* L_kj_w       = (const float*)d_in[14];
    const float* L_kj_b       = (const float*)d_in[15];
    const float* L_sbf1_w     = (const float*)d_in[16];
    const float* L_sbf2_w     = (const float*)d_in[17];
    const float* L_down_w     = (const float*)d_in[18];
    const float* L_down_b     = (const float*)d_in[19];
    const float* L_up_w       = (const float*)d_in[20];
    const float* L_up_b       = (const float*)d_in[21];
    const float* L_res1_w     = (const float*)d_in[22];
    const float* L_res1_b     = (const float*)d_in[23];
    const float* L_res2_w     = (const float*)d_in[24];
    const float* L_res2_b     = (const float*)d_in[25];
    const float* W_o_w        = (const float*)d_in[26];
    const float* W_o_b        = (const float*)d_in[27];
    const int* idx_i          = (const int*)d_in[28];
    const int* idx_j          = (const int*)d_in[29];
    const int* idx_kj         = (const int*)d_in[30];
    const int* ib_eid         = (const int*)d_in[32];
    const int* ib_atom        = (const int*)d_in[33];

    float* ws = (float*)d_ws;
    size_t off = 0;
    auto take = [&](size_t n) { float* p = ws + off; off += n; return p; };
    float* msg   = take((size_t)Ecnt * 128);
    short* rbfe  = (short*)take((size_t)Ecnt * 64);
    short* sxd   = (short*)take((size_t)Ecnt * 64);
    short* ysort = (short*)take((size_t)Tcnt * 64);
    float* rbf0b = take((size_t)Ecnt * 16);
    float* P1    = take(100 * 128);
    float* P2    = take(100 * 128);
    int*   atyp  = (int*)take(Ncnt);
    int*   cnts  = (int*)take(Ecnt);
    int*   sstart= (int*)take(Ecnt + 1);
    int*   cur   = (int*)take(Ecnt);
    int*   btot  = (int*)take(512);
    int*   boff  = (int*)take(512);
    int*   eids  = (int*)take(Tcnt);
    float* angs  = take(Tcnt);
    short* wts   = (short*)take(160000);

    if (off * sizeof(float) > ws_size) {
        sentinel_k<<<1, 256, 0, stream>>>((float*)d_out, (float)ws_size);
        return;
    }

    float* rbfh_s = (float*)ysort;
    float* atomm  = (float*)ysort;

    const int GE  = Ecnt / 64;
    const int GN  = (Ncnt + 63) / 64;
    const int NBE = (Ecnt + 255) / 256;
    const int NBT = (Tcnt + 255) / 256;

    atype_k<<<(Ncnt + 255) / 256, 256, 0, stream>>>(atom_feature, atyp);
    pemb_k<<<100, 128, 0, stream>>>(emb_table, lin_emb_w, P1, P2);
    rbf0_k<<<NBE, 256, 0, stream>>>(dist, bessel_freq, rbf0b);

    hipMemsetAsync(cnts, 0, (size_t)Ecnt * sizeof(int), stream);
    hist_k<<<NBT, 256, 0, stream>>>(idx_kj, cnts);
    scan1_k<<<NBE, 256, 0, stream>>>(cnts, btot);
    scan2_k<<<1, 512, 0, stream>>>(btot, boff, NBE);
    scan3_k<<<NBE, 256, 0, stream>>>(cnts, boff, sstart, cur);
    perm_k<<<NBT, 256, 0, stream>>>(idx_kj, angle, cur, eids, angs);

    short* p = wts;
    short* wt1[2]; short* wt2[2]; short* wt3[2];
    short* wkj[2]; short* wr2f[2]; short* wdn[2]; short* wr1[2]; short* wr2[2];
    for (int l = 0; l < 2; ++l) {
        wt1[l] = p; p += 96 * 128;
        wt2[l] = p; p += 128 * 128;
        wt3[l] = p; p += 128 * 128;
        wkj[l] = p; p += 128 * 128;
        wr2f[l] = p; p += 128 * 128;
        wdn[l] = p; p += 128 * 128;
        wr1[l] = p; p += 128 * 128;
        wr2[l] = p; p += 128 * 128;
    }
    short* wemb3 = p; p += 128 * 128;
    short* wi1t  = p; p += 128 * 160;

    // E-path weights: [col][K] transposed layout
    WPack wp;
    int m = 0;
    for (int l = 0; l < 2; ++l) {
        wp.src[m] = L_kj_w   + (size_t)l * 128 * 128; wp.dst[m++] = wkj[l];
        wp.src[m] = L_rbf2_w + (size_t)l * 128 * 128; wp.dst[m++] = wr2f[l];
        wp.src[m] = L_down_w + (size_t)l * 128 * 128; wp.dst[m++] = wdn[l];
        wp.src[m] = L_res2_w + (size_t)l * 128 * 128; wp.dst[m++] = wr2[l];
    }
    wp.src[m] = lin_emb_w + 256 * 128; wp.dst[m++] = wemb3;   // m == 9
    transmany_k<<<9 * 64, 256, 0, stream>>>(wp);

    // T-path weights: fragment-major layout for LDS residency
    for (int l = 0; l < 2; ++l) {
        transfrag_k<<<48, 256, 0, stream>>>(L_sbf1_w + (size_t)l * 96 * 128,  wt1[l], 3);
        transfrag_k<<<64, 256, 0, stream>>>(L_sbf2_w + (size_t)l * 128 * 128, wt2[l], 4);
        transfrag_k<<<64, 256, 0, stream>>>(L_up_w   + (size_t)l * 128 * 128, wt3[l], 4);
    }
    const int G128 = (128 * 128 + 255) / 256;
    transperm_k<<<G128, 256, 0, stream>>>(L_res1_w, wr1[0]);
    transperm_k<<<G128, 256, 0, stream>>>(L_res1_w + (size_t)128 * 128, wr1[1]);
    transWi1_k<<<(128 * 160 + 255) / 256, 256, 0, stream>>>(W_i1_w, wi1t);

    imsg_k<<<GE, 256, 0, stream>>>(atom_feature, edge_feature, idx_j, wi1t, W_i1_b, msg);
    rbfh_k<<<(Ecnt * 128) / 256, 256, 0, stream>>>(rbf0b, lin_rbf_w, lin_rbf_b, rbfh_s);
    rbfe_k<<<GE, 256, 0, stream>>>(rbfh_s, wemb3, lin_emb_b, idx_i, idx_j, atyp, P1, P2, rbfe);

    for (int l = 0; l < 2; ++l) {
        layerA_k<<<GE, 256, 0, stream>>>(msg, rbfe,
                                         wkj[l], L_kj_b + (size_t)l * 128,
                                         wr2f[l], L_rbf2_b + (size_t)l * 128,
                                         wdn[l], L_down_b + (size_t)l * 128, sxd);
        triplet_mfma_k<<<512, 512, 0, stream>>>(angs, eids, rbf0b,
                                                wt1[l], wt2[l], wt3[l],
                                                L_up_b + (size_t)l * 128, sxd, ysort);
        layerBf_k<<<GE, 256, 0, stream>>>(ysort, sstart,
                                          wr1[l], L_res1_b + (size_t)l * 128,
                                          wr2[l], L_res2_b + (size_t)l * 128, msg);
    }

    hipMemsetAsync(atomm, 0, (size_t)Ncnt * 128 * sizeof(float), stream);
    scatatom_k<<<(Ecnt * 128) / 256, 256, 0, stream>>>(msg, ib_eid, ib_atom, atomm);
    concatgemm_k<<<GN, 256, 0, stream>>>(atom_feature, 133, atomm, 128,
                                         W_o_w, W_o_b, (float*)d_out, Ncnt);
}